// Round 1
// baseline (1069.289 us; speedup 1.0000x reference)
//
#include <hip/hip_runtime.h>
#include <math.h>

#define BB 4
#define SS 2048
#define HH 256
#define DD 64
#define NLAYERS 2

__device__ __forceinline__ float lrelu(float v) { return v > 0.f ? v : 0.01f * v; }

// ---------------------------------------------------------------------------
// Generic f32 GEMM: C[M,N] = A[M,K] @ B (+bias[j]) (relu) (+res[i,j])
// transB=0: B is [K,N] row-major. transB=1: B is [N,K] row-major.
// 64x64 tile, K-chunk 32, 256 threads, 4x4 acc/thread.
// ---------------------------------------------------------------------------
__global__ __launch_bounds__(256) void gemm64(
    const float* __restrict__ A, long sAb, int lda,
    const float* __restrict__ Bm, long sBb,
    const float* __restrict__ bias,
    const float* __restrict__ res,
    float* __restrict__ C, long sCb,
    int M, int N, int K, int transB, int doRelu)
{
    __shared__ float As[32][68];
    __shared__ float Bs[32][68];
    const int b = blockIdx.z;
    const float* Ab = A + (long)b * sAb;
    const float* Bb = Bm + (long)b * sBb;
    float* Cb = C + (long)b * sCb;
    const int i0 = blockIdx.x * 64, j0 = blockIdx.y * 64;
    const int tid = threadIdx.x;
    const int tx = tid & 15, ty = tid >> 4;
    float acc[4][4] = {};

    for (int k0 = 0; k0 < K; k0 += 32) {
        {   // A tile 64x32 -> As[k][i]
            int c = tid & 31, r0 = tid >> 5;
            #pragma unroll
            for (int p = 0; p < 8; ++p) {
                int r = r0 + 8 * p;
                As[c][r] = Ab[(long)(i0 + r) * lda + (k0 + c)];
            }
        }
        if (!transB) {  // B tile 32x64 -> Bs[k][j]
            int c = tid & 63, r0 = tid >> 6;
            #pragma unroll
            for (int p = 0; p < 8; ++p) {
                int r = r0 + 4 * p;
                Bs[r][c] = Bb[(long)(k0 + r) * N + (j0 + c)];
            }
        } else {        // B is [N,K]: Bs[k][n] = B[n][k]
            int c = tid & 31, r0 = tid >> 5;
            #pragma unroll
            for (int p = 0; p < 8; ++p) {
                int n = r0 + 8 * p;
                Bs[c][n] = Bb[(long)(j0 + n) * K + (k0 + c)];
            }
        }
        __syncthreads();
        #pragma unroll
        for (int kk = 0; kk < 32; ++kk) {
            float4 a4 = *(const float4*)&As[kk][4 * ty];
            float4 b4 = *(const float4*)&Bs[kk][4 * tx];
            float av[4] = {a4.x, a4.y, a4.z, a4.w};
            float bv[4] = {b4.x, b4.y, b4.z, b4.w};
            #pragma unroll
            for (int r = 0; r < 4; ++r)
                #pragma unroll
                for (int cc = 0; cc < 4; ++cc)
                    acc[r][cc] += av[r] * bv[cc];
        }
        __syncthreads();
    }
    #pragma unroll
    for (int r = 0; r < 4; ++r) {
        int i = i0 + 4 * ty + r;
        #pragma unroll
        for (int cc = 0; cc < 4; ++cc) {
            int j = j0 + 4 * tx + cc;
            float v = acc[r][cc];
            if (bias) v += bias[j];
            if (doRelu) v = fmaxf(v, 0.f);
            if (res) v += res[(long)i * N + j];
            Cb[(long)i * N + j] = v;
        }
    }
}

// f[s] = sum_d ft[s,d] * attn_a[d]   (one wave per row)
__global__ __launch_bounds__(256) void compute_f(
    const float* __restrict__ ft, const float* __restrict__ aa, float* __restrict__ f)
{
    int wave = threadIdx.x >> 6, lane = threadIdx.x & 63;
    int s = blockIdx.x * 4 + wave;
    float v = ft[(long)s * DD + lane] * aa[lane];
    #pragma unroll
    for (int off = 32; off; off >>= 1) v += __shfl_down(v, off, 64);
    if (lane == 0) f[s] = v;
}

// Column softmax stats (axis=1 -> reduce over i for each column j), 8-way i-split.
__global__ __launch_bounds__(256) void col_stats_part(
    const float* __restrict__ biasb,   // points at biases[:,1]; batch stride 2*S*S
    const float* __restrict__ f,
    float* __restrict__ partM, float* __restrict__ partS)
{
    int b = blockIdx.z;
    int j = blockIdx.x * 256 + threadIdx.x;
    int chunk = blockIdx.y;
    const float* bb = biasb + (long)b * 2 * SS * SS;
    float fj = f[b * SS + j];
    float m = -1e30f, s = 0.f;
    int ibase = chunk * 256;
    for (int ii = 0; ii < 256; ++ii) {
        int i = ibase + ii;
        float l = lrelu(f[b * SS + i] + fj) + bb[(long)i * SS + j];
        if (l > m) { s = s * __expf(m - l) + 1.f; m = l; }
        else s += __expf(l - m);
    }
    partM[(chunk * BB + b) * SS + j] = m;
    partS[(chunk * BB + b) * SS + j] = s;
}

__global__ __launch_bounds__(256) void col_stats_merge(
    const float* __restrict__ partM, const float* __restrict__ partS,
    float* __restrict__ Mv, float* __restrict__ Sinv)
{
    int idx = blockIdx.x * 256 + threadIdx.x;   // b*S + j
    int b = idx / SS, j = idx % SS;
    float m = -1e30f;
    #pragma unroll
    for (int c = 0; c < 8; ++c) m = fmaxf(m, partM[(c * BB + b) * SS + j]);
    float s = 0.f;
    #pragma unroll
    for (int c = 0; c < 8; ++c)
        s += partS[(c * BB + b) * SS + j] * __expf(partM[(c * BB + b) * SS + j] - m);
    Mv[idx] = m;
    Sinv[idx] = 1.f / s;
}

// PV partial: pvp[half][b][i][d] = sum_{j in half} w_ij * ft[j,d]
// w_ij = exp(lrelu(f_i+f_j)+bias[i,j] - m_j) * sinv_j
__global__ __launch_bounds__(256) void pv_part(
    const float* __restrict__ biasb, const float* __restrict__ f,
    const float* __restrict__ Mv, const float* __restrict__ Sinv,
    const float* __restrict__ ft, float* __restrict__ pvp)
{
    __shared__ float fts[32][68];
    __shared__ float wlds[64][36];
    int b = blockIdx.z;
    int i0 = blockIdx.y * 64;
    int half = blockIdx.x;
    const float* bb = biasb + (long)b * 2 * SS * SS;
    int tid = threadIdx.x;
    int tx = tid & 15, ty = tid >> 4;
    float acc[4][4] = {};

    for (int j0 = half * 1024; j0 < half * 1024 + 1024; j0 += 32) {
        #pragma unroll
        for (int p = 0; p < 2; ++p) {  // stage ft[j0:j0+32, 0:64]
            int q = tid + 256 * p;
            int jj = q >> 4, dd = (q & 15) << 2;
            *(float4*)&fts[jj][dd] =
                *(const float4*)&ft[((long)(b * SS + j0 + jj)) * DD + dd];
        }
        {   // compute w tile 64 x 32
            int jl = tid & 31, il0 = tid >> 5;
            int j = j0 + jl;
            float fj = f[b * SS + j];
            float mj = Mv[b * SS + j];
            float sj = Sinv[b * SS + j];
            #pragma unroll
            for (int p = 0; p < 8; ++p) {
                int il = il0 + 8 * p;
                int i = i0 + il;
                float l = lrelu(f[b * SS + i] + fj) + bb[(long)i * SS + j];
                wlds[il][jl] = __expf(l - mj) * sj;
            }
        }
        __syncthreads();
        #pragma unroll
        for (int jj4 = 0; jj4 < 32; jj4 += 4) {
            float fvv[4][4];
            #pragma unroll
            for (int t = 0; t < 4; ++t) {
                float4 fv = *(const float4*)&fts[jj4 + t][4 * tx];
                fvv[t][0] = fv.x; fvv[t][1] = fv.y; fvv[t][2] = fv.z; fvv[t][3] = fv.w;
            }
            #pragma unroll
            for (int r = 0; r < 4; ++r) {
                float4 wv = *(const float4*)&wlds[4 * ty + r][jj4];
                float wr[4] = {wv.x, wv.y, wv.z, wv.w};
                #pragma unroll
                for (int t = 0; t < 4; ++t)
                    #pragma unroll
                    for (int cc = 0; cc < 4; ++cc)
                        acc[r][cc] += wr[t] * fvv[t][cc];
            }
        }
        __syncthreads();
    }
    #pragma unroll
    for (int r = 0; r < 4; ++r) {
        int i = i0 + 4 * ty + r;
        float4 o = {acc[r][0], acc[r][1], acc[r][2], acc[r][3]};
        *(float4*)&pvp[(((long)half * BB + b) * SS + i) * DD + 4 * tx] = o;
    }
}

// x_out = tile(leaky(pv0+pv1), HEADS) + x_in
__global__ __launch_bounds__(256) void pv_combine(
    const float* __restrict__ pvp, const float* __restrict__ xin, float* __restrict__ xout)
{
    long idx = (long)blockIdx.x * 256 + threadIdx.x;  // B*S*16 float4-groups
    long row = idx >> 4;
    int dq = (int)(idx & 15) << 2;
    float4 p0 = *(const float4*)&pvp[(row) * DD + dq];
    float4 p1 = *(const float4*)&pvp[((long)BB * SS + row) * DD + dq];
    float r0 = lrelu(p0.x + p1.x), r1 = lrelu(p0.y + p1.y);
    float r2 = lrelu(p0.z + p1.z), r3 = lrelu(p0.w + p1.w);
    #pragma unroll
    for (int rep = 0; rep < 4; ++rep) {
        long off = row * HH + rep * DD + dq;
        float4 xi = *(const float4*)&xin[off];
        float4 o = {r0 + xi.x, r1 + xi.y, r2 + xi.z, r3 + xi.w};
        *(float4*)&xout[off] = o;
    }
}

// g = ln_a*(x-mean)/(std_ddof1 + eps) + ln_b + x0     (block = one row of 256)
__global__ __launch_bounds__(256) void layernorm_g(
    const float* __restrict__ x, const float* __restrict__ x0,
    const float* __restrict__ lna, const float* __restrict__ lnb,
    float* __restrict__ g)
{
    __shared__ float red[8];
    long row = blockIdx.x;
    int t = threadIdx.x;
    int wave = t >> 6, lane = t & 63;
    float v = x[row * HH + t];

    float sum = v;
    #pragma unroll
    for (int off = 32; off; off >>= 1) sum += __shfl_down(sum, off, 64);
    if (lane == 0) red[wave] = sum;
    __syncthreads();
    if (t < 64) {
        float s = (lane < 4) ? red[lane] : 0.f;
        s += __shfl_down(s, 2, 64);
        s += __shfl_down(s, 1, 64);
        if (lane == 0) red[4] = s / HH;
    }
    __syncthreads();
    float mean = red[4];
    float d = v - mean;
    float sq = d * d;
    #pragma unroll
    for (int off = 32; off; off >>= 1) sq += __shfl_down(sq, off, 64);
    __syncthreads();            // everyone has read red[4]
    if (lane == 0) red[wave] = sq;
    __syncthreads();
    if (t < 64) {
        float s = (lane < 4) ? red[lane] : 0.f;
        s += __shfl_down(s, 2, 64);
        s += __shfl_down(s, 1, 64);
        if (lane == 0) red[5] = sqrtf(s / (HH - 1));
    }
    __syncthreads();
    float stdv = red[5];
    g[row * HH + t] = lna[t] * d / (stdv + 1e-6f) + lnb[t] + x0[row * HH + t];
}

extern "C" void kernel_launch(void* const* d_in, const int* in_sizes, int n_in,
                              void* d_out, int out_size, void* d_ws, size_t ws_size,
                              hipStream_t stream)
{
    const float* inputs = (const float*)d_in[0];
    const float* graphs = (const float*)d_in[1];
    const float* biases = (const float*)d_in[2];
    const float* gc_w   = (const float*)d_in[3];
    const float* gc_b   = (const float*)d_in[4];
    const float* attn_w = (const float*)d_in[5];
    const float* attn_a = (const float*)d_in[6];
    const float* ln_a   = (const float*)d_in[7];
    const float* ln_b   = (const float*)d_in[8];
    const float* w1     = (const float*)d_in[9];
    const float* w1b    = (const float*)d_in[10];
    const float* w2     = (const float*)d_in[11];
    const float* w2b    = (const float*)d_in[12];
    float* out = (float*)d_out;

    float* ws = (float*)d_ws;
    float* X  = ws;                 // 2,097,152
    float* XW = ws + 2097152;       // 2,097,152   (later: G)
    float* MF = ws + 4194304;       // 2,097,152   (later: PV partials, then H1)
    float* PV = MF;                 // 1,048,576 (mf dead when PV is live)
    float* FT = ws + 6291456;       // 524,288
    float* F  = ws + 6815744;       // 8,192
    float* Mv = ws + 6823936;       // 8,192
    float* Sv = ws + 6832128;       // 8,192
    float* PM = ws + 6840320;       // 65,536
    float* PS = ws + 6905856;       // 65,536  -> end 6,971,392 floats (~27.9 MB)

    const float* adjBase  = graphs + (long)SS * SS;  // [:, TYPE_IDX=1]
    const float* biasBase = biases + (long)SS * SS;
    const long   batStride = (long)2 * SS * SS;

    const float* xin = inputs;
    for (int L = 0; L < NLAYERS; ++L) {
        // xw = x @ gc_w[L]
        gemm64<<<dim3(128, 4, 1), 256, 0, stream>>>(
            xin, 0, HH, gc_w + (long)L * HH * HH, 0,
            nullptr, nullptr, XW, 0, BB * SS, HH, HH, 0, 0);
        // mf = adj @ xw + gc_b[L]   (batched)
        gemm64<<<dim3(32, 4, BB), 256, 0, stream>>>(
            adjBase, batStride, SS, XW, (long)SS * HH,
            gc_b + L * HH, nullptr, MF, (long)SS * HH, SS, HH, SS, 0, 0);
        // ft = mf @ attn_w[L]^T
        gemm64<<<dim3(128, 1, 1), 256, 0, stream>>>(
            MF, 0, HH, attn_w + (long)L * DD * HH, 0,
            nullptr, nullptr, FT, 0, BB * SS, DD, HH, 1, 0);
        // f = ft @ attn_a[L]
        compute_f<<<2048, 256, 0, stream>>>(FT, attn_a + L * DD, F);
        // column softmax stats
        col_stats_part<<<dim3(8, 8, BB), 256, 0, stream>>>(biasBase, F, PM, PS);
        col_stats_merge<<<32, 256, 0, stream>>>(PM, PS, Mv, Sv);
        // PV partials (2 j-halves), then combine + leaky + tile + residual
        pv_part<<<dim3(2, 32, BB), 256, 0, stream>>>(biasBase, F, Mv, Sv, FT, PV);
        pv_combine<<<512, 256, 0, stream>>>(PV, xin, X);
        xin = X;
    }

    float* G  = XW;
    float* H1 = MF;
    layernorm_g<<<BB * SS, 256, 0, stream>>>(X, inputs, ln_a, ln_b, G);
    // h1 = relu(g @ w1^T + w1b)
    gemm64<<<dim3(128, 4, 1), 256, 0, stream>>>(
        G, 0, HH, w1, 0, w1b, nullptr, H1, 0, BB * SS, HH, HH, 1, 1);
    // out = h1 @ w2^T + w2b + g
    gemm64<<<dim3(128, 4, 1), 256, 0, stream>>>(
        H1, 0, HH, w2, 0, w2b, G, out, 0, BB * SS, HH, HH, 1, 0);
}

// Round 2
// 490.369 us; speedup vs baseline: 2.1806x; 2.1806x over previous
//
#include <hip/hip_runtime.h>
#include <math.h>

#define BB 4
#define SS 2048
#define HH 256
#define DD 64
#define NLAYERS 2

__device__ __forceinline__ float lrelu(float v) { return v > 0.f ? v : 0.01f * v; }

// ---------------------------------------------------------------------------
// Generic f32 GEMM: C[M,N] = A[M,K] @ B (+bias[j]) (relu) (+res[i,j])
// transB=0: B is [K,N] row-major. transB=1: B is [N,K] row-major.
// 64x64 tile, K-chunk 32, 256 threads, 4x4 acc/thread.
// ---------------------------------------------------------------------------
__global__ __launch_bounds__(256) void gemm64(
    const float* __restrict__ A, long sAb, int lda,
    const float* __restrict__ Bm, long sBb,
    const float* __restrict__ bias,
    const float* __restrict__ res,
    float* __restrict__ C, long sCb,
    int M, int N, int K, int transB, int doRelu)
{
    __shared__ float As[32][68];
    __shared__ float Bs[32][68];
    const int b = blockIdx.z;
    const float* Ab = A + (long)b * sAb;
    const float* Bb = Bm + (long)b * sBb;
    float* Cb = C + (long)b * sCb;
    const int i0 = blockIdx.x * 64, j0 = blockIdx.y * 64;
    const int tid = threadIdx.x;
    const int tx = tid & 15, ty = tid >> 4;
    float acc[4][4] = {};

    for (int k0 = 0; k0 < K; k0 += 32) {
        {   // A tile 64x32 -> As[k][i]
            int c = tid & 31, r0 = tid >> 5;
            #pragma unroll
            for (int p = 0; p < 8; ++p) {
                int r = r0 + 8 * p;
                As[c][r] = Ab[(long)(i0 + r) * lda + (k0 + c)];
            }
        }
        if (!transB) {  // B tile 32x64 -> Bs[k][j]
            int c = tid & 63, r0 = tid >> 6;
            #pragma unroll
            for (int p = 0; p < 8; ++p) {
                int r = r0 + 4 * p;
                Bs[r][c] = Bb[(long)(k0 + r) * N + (j0 + c)];
            }
        } else {        // B is [N,K]: Bs[k][n] = B[n][k]
            int c = tid & 31, r0 = tid >> 5;
            #pragma unroll
            for (int p = 0; p < 8; ++p) {
                int n = r0 + 8 * p;
                Bs[c][n] = Bb[(long)(j0 + n) * K + (k0 + c)];
            }
        }
        __syncthreads();
        #pragma unroll
        for (int kk = 0; kk < 32; ++kk) {
            float4 a4 = *(const float4*)&As[kk][4 * ty];
            float4 b4 = *(const float4*)&Bs[kk][4 * tx];
            float av[4] = {a4.x, a4.y, a4.z, a4.w};
            float bv[4] = {b4.x, b4.y, b4.z, b4.w};
            #pragma unroll
            for (int r = 0; r < 4; ++r)
                #pragma unroll
                for (int cc = 0; cc < 4; ++cc)
                    acc[r][cc] += av[r] * bv[cc];
        }
        __syncthreads();
    }
    #pragma unroll
    for (int r = 0; r < 4; ++r) {
        int i = i0 + 4 * ty + r;
        #pragma unroll
        for (int cc = 0; cc < 4; ++cc) {
            int j = j0 + 4 * tx + cc;
            float v = acc[r][cc];
            if (bias) v += bias[j];
            if (doRelu) v = fmaxf(v, 0.f);
            if (res) v += res[(long)i * N + j];
            Cb[(long)i * N + j] = v;
        }
    }
}

// W_y[L][h][d] = sum_h' gc_w[L][h][h'] * attn_w[L][d][h'];  b_y[L][d] = gc_b[L]@attn_w[L][d]
__global__ __launch_bounds__(256) void prep_wy(
    const float* __restrict__ gc_w, const float* __restrict__ gc_b,
    const float* __restrict__ attn_w, float* __restrict__ Wy, float* __restrict__ by)
{
    int L = blockIdx.x >> 6, d = blockIdx.x & 63;
    int h = threadIdx.x;
    const float* gw = gc_w + (long)L * HH * HH;
    const float* aw = attn_w + (long)L * DD * HH + (long)d * HH;
    float acc = 0.f;
    for (int hp = 0; hp < HH; ++hp) acc += gw[(long)h * HH + hp] * aw[hp];
    Wy[((long)L * HH + h) * DD + d] = acc;
    if (h == 0) {
        float ba = 0.f;
        const float* gb = gc_b + (long)L * HH;
        for (int hp = 0; hp < HH; ++hp) ba += gb[hp] * aw[hp];
        by[L * DD + d] = ba;
    }
}

// FTP[ky][b][i][d] partial of adj@y over K-slice ky (256 k's each)
__global__ __launch_bounds__(256) void ftp_gemm(
    const float* __restrict__ adjB, const float* __restrict__ Y,
    float* __restrict__ FTP)
{
    __shared__ float As[32][68];   // [k][i]
    __shared__ float Bs[32][68];   // [k][d]
    const int b = blockIdx.z;
    const int i0 = blockIdx.x * 64;
    const int ky = blockIdx.y;
    const float* A = adjB + (long)b * 2 * SS * SS;
    const int tid = threadIdx.x;
    const int tx = tid & 15, ty = tid >> 4;
    float acc[4][4] = {};

    for (int kc = 0; kc < 256; kc += 32) {
        int k0 = ky * 256 + kc;
        {   // adj tile 64 x 32
            int c = tid & 31, r0 = tid >> 5;
            #pragma unroll
            for (int p = 0; p < 8; ++p) {
                int r = r0 + 8 * p;
                As[c][r] = A[(long)(i0 + r) * SS + (k0 + c)];
            }
        }
        {   // y tile 32 x 64
            int d = tid & 63, r0 = tid >> 6;
            #pragma unroll
            for (int p = 0; p < 8; ++p) {
                int r = r0 + 4 * p;
                Bs[r][d] = Y[((long)b * SS + k0 + r) * DD + d];
            }
        }
        __syncthreads();
        #pragma unroll
        for (int kk = 0; kk < 32; ++kk) {
            float4 a4 = *(const float4*)&As[kk][4 * ty];
            float4 b4 = *(const float4*)&Bs[kk][4 * tx];
            float av[4] = {a4.x, a4.y, a4.z, a4.w};
            float bv[4] = {b4.x, b4.y, b4.z, b4.w};
            #pragma unroll
            for (int r = 0; r < 4; ++r)
                #pragma unroll
                for (int cc = 0; cc < 4; ++cc)
                    acc[r][cc] += av[r] * bv[cc];
        }
        __syncthreads();
    }
    #pragma unroll
    for (int r = 0; r < 4; ++r) {
        long i = i0 + 4 * ty + r;
        float4 o = {acc[r][0], acc[r][1], acc[r][2], acc[r][3]};
        *(float4*)&FTP[(((long)ky * BB + b) * SS + i) * DD + 4 * tx] = o;
    }
}

// FT[row][d] = sum_ky FTP + b_y[d];  F[row] = FT[row][:]@attn_a
__global__ __launch_bounds__(256) void reduce_ft_f(
    const float* __restrict__ FTP, const float* __restrict__ byL,
    const float* __restrict__ aaL, float* __restrict__ FT, float* __restrict__ F)
{
    int row = blockIdx.x * 4 + (threadIdx.x >> 6);
    int d = threadIdx.x & 63;
    float v = byL[d];
    #pragma unroll
    for (int sk = 0; sk < 8; ++sk)
        v += FTP[((long)sk * BB * SS + row) * DD + d];
    FT[(long)row * DD + d] = v;
    float t = v * aaL[d];
    #pragma unroll
    for (int off = 32; off; off >>= 1) t += __shfl_down(t, off, 64);
    if (d == 0) F[row] = t;
}

// Column softmax stats (reduce over i for each column j), 8-way i-split.
__global__ __launch_bounds__(256) void col_stats_part(
    const float* __restrict__ biasb, const float* __restrict__ f,
    float* __restrict__ partM, float* __restrict__ partS)
{
    int b = blockIdx.z;
    int j = blockIdx.x * 256 + threadIdx.x;
    int chunk = blockIdx.y;
    const float* bb = biasb + (long)b * 2 * SS * SS;
    float fj = f[b * SS + j];
    float m = -1e30f, s = 0.f;
    int ibase = chunk * 256;
    for (int ii = 0; ii < 256; ++ii) {
        int i = ibase + ii;
        float l = lrelu(f[b * SS + i] + fj) + bb[(long)i * SS + j];
        if (l > m) { s = s * __expf(m - l) + 1.f; m = l; }
        else s += __expf(l - m);
    }
    partM[(chunk * BB + b) * SS + j] = m;
    partS[(chunk * BB + b) * SS + j] = s;
}

__global__ __launch_bounds__(256) void col_stats_merge(
    const float* __restrict__ partM, const float* __restrict__ partS,
    float* __restrict__ Mv, float* __restrict__ Sinv)
{
    int idx = blockIdx.x * 256 + threadIdx.x;   // b*S + j
    int b = idx / SS, j = idx % SS;
    float m = -1e30f;
    #pragma unroll
    for (int c = 0; c < 8; ++c) m = fmaxf(m, partM[(c * BB + b) * SS + j]);
    float s = 0.f;
    #pragma unroll
    for (int c = 0; c < 8; ++c)
        s += partS[(c * BB + b) * SS + j] * __expf(partM[(c * BB + b) * SS + j] - m);
    Mv[idx] = m;
    Sinv[idx] = 1.f / s;
}

// PVP[jy][b][i][d] = sum_{j in slice jy} w_ij * ft[j,d]
__global__ __launch_bounds__(256) void pvp_gemm(
    const float* __restrict__ biasb, const float* __restrict__ f,
    const float* __restrict__ Mv, const float* __restrict__ Sinv,
    const float* __restrict__ FT, float* __restrict__ PVP)
{
    __shared__ float fts[32][68];
    __shared__ float wlds[64][36];
    const int b = blockIdx.z;
    const int i0 = blockIdx.x * 64;
    const int jy = blockIdx.y;
    const float* bb = biasb + (long)b * 2 * SS * SS;
    const int tid = threadIdx.x;
    const int tx = tid & 15, ty = tid >> 4;
    float acc[4][4] = {};

    for (int jc = 0; jc < 256; jc += 32) {
        int j0 = jy * 256 + jc;
        #pragma unroll
        for (int p = 0; p < 2; ++p) {  // stage ft[j0:j0+32, 0:64]
            int q = tid + 256 * p;
            int jj = q >> 4, dd = (q & 15) << 2;
            *(float4*)&fts[jj][dd] =
                *(const float4*)&FT[((long)(b * SS + j0 + jj)) * DD + dd];
        }
        {   // w tile 64 x 32
            int jl = tid & 31, il0 = tid >> 5;
            int j = j0 + jl;
            float fj = f[b * SS + j];
            float mj = Mv[b * SS + j];
            float sj = Sinv[b * SS + j];
            #pragma unroll
            for (int p = 0; p < 8; ++p) {
                int il = il0 + 8 * p;
                int i = i0 + il;
                float l = lrelu(f[b * SS + i] + fj) + bb[(long)i * SS + j];
                wlds[il][jl] = __expf(l - mj) * sj;
            }
        }
        __syncthreads();
        #pragma unroll
        for (int jj4 = 0; jj4 < 32; jj4 += 4) {
            float fvv[4][4];
            #pragma unroll
            for (int t = 0; t < 4; ++t) {
                float4 fv = *(const float4*)&fts[jj4 + t][4 * tx];
                fvv[t][0] = fv.x; fvv[t][1] = fv.y; fvv[t][2] = fv.z; fvv[t][3] = fv.w;
            }
            #pragma unroll
            for (int r = 0; r < 4; ++r) {
                float4 wv = *(const float4*)&wlds[4 * ty + r][jj4];
                float wr[4] = {wv.x, wv.y, wv.z, wv.w};
                #pragma unroll
                for (int t = 0; t < 4; ++t)
                    #pragma unroll
                    for (int cc = 0; cc < 4; ++cc)
                        acc[r][cc] += wr[t] * fvv[t][cc];
            }
        }
        __syncthreads();
    }
    #pragma unroll
    for (int r = 0; r < 4; ++r) {
        long i = i0 + 4 * ty + r;
        float4 o = {acc[r][0], acc[r][1], acc[r][2], acc[r][3]};
        *(float4*)&PVP[(((long)jy * BB + b) * SS + i) * DD + 4 * tx] = o;
    }
}

// x_out = tile(lrelu(sum_jy PVP), HEADS) + x_in
__global__ __launch_bounds__(256) void pv_combine8(
    const float* __restrict__ PVP, const float* __restrict__ xin, float* __restrict__ xout)
{
    int row = blockIdx.x * 4 + (threadIdx.x >> 6);
    int d = threadIdx.x & 63;
    float v = 0.f;
    #pragma unroll
    for (int jy = 0; jy < 8; ++jy)
        v += PVP[((long)jy * BB * SS + row) * DD + d];
    v = lrelu(v);
    #pragma unroll
    for (int rep = 0; rep < 4; ++rep) {
        long off = (long)row * HH + rep * DD + d;
        xout[off] = v + xin[off];
    }
}

// g = ln_a*(x-mean)/(std_ddof1 + eps) + ln_b + x0     (block = one row of 256)
__global__ __launch_bounds__(256) void layernorm_g(
    const float* __restrict__ x, const float* __restrict__ x0,
    const float* __restrict__ lna, const float* __restrict__ lnb,
    float* __restrict__ g)
{
    __shared__ float red[8];
    long row = blockIdx.x;
    int t = threadIdx.x;
    int wave = t >> 6, lane = t & 63;
    float v = x[row * HH + t];

    float sum = v;
    #pragma unroll
    for (int off = 32; off; off >>= 1) sum += __shfl_down(sum, off, 64);
    if (lane == 0) red[wave] = sum;
    __syncthreads();
    if (t < 64) {
        float s = (lane < 4) ? red[lane] : 0.f;
        s += __shfl_down(s, 2, 64);
        s += __shfl_down(s, 1, 64);
        if (lane == 0) red[4] = s / HH;
    }
    __syncthreads();
    float mean = red[4];
    float d = v - mean;
    float sq = d * d;
    #pragma unroll
    for (int off = 32; off; off >>= 1) sq += __shfl_down(sq, off, 64);
    __syncthreads();
    if (lane == 0) red[wave] = sq;
    __syncthreads();
    if (t < 64) {
        float s = (lane < 4) ? red[lane] : 0.f;
        s += __shfl_down(s, 2, 64);
        s += __shfl_down(s, 1, 64);
        if (lane == 0) red[5] = sqrtf(s / (HH - 1));
    }
    __syncthreads();
    float stdv = red[5];
    g[row * HH + t] = lna[t] * d / (stdv + 1e-6f) + lnb[t] + x0[row * HH + t];
}

extern "C" void kernel_launch(void* const* d_in, const int* in_sizes, int n_in,
                              void* d_out, int out_size, void* d_ws, size_t ws_size,
                              hipStream_t stream)
{
    const float* inputs = (const float*)d_in[0];
    const float* graphs = (const float*)d_in[1];
    const float* biases = (const float*)d_in[2];
    const float* gc_w   = (const float*)d_in[3];
    const float* gc_b   = (const float*)d_in[4];
    const float* attn_w = (const float*)d_in[5];
    const float* attn_a = (const float*)d_in[6];
    const float* ln_a   = (const float*)d_in[7];
    const float* ln_b   = (const float*)d_in[8];
    const float* w1     = (const float*)d_in[9];
    const float* w1b    = (const float*)d_in[10];
    const float* w2     = (const float*)d_in[11];
    const float* w2b    = (const float*)d_in[12];
    float* out = (float*)d_out;

    // ---- workspace layout (floats), total 6,873,216 (~27.5 MB) ----
    float* ws  = (float*)d_ws;
    float* X   = ws;                        // 2,097,152
    float* REG = ws + 2097152;              // 4,194,304: FTP[0:8]/PVP[0:8]/PM,PS/G,H1
    float* YFT = ws + 6291456;              // 524,288 (y, then ft)
    float* F   = ws + 6815744;              // 8,192
    float* Mv  = ws + 6823936;              // 8,192
    float* Sv  = ws + 6832128;              // 8,192
    float* Wy  = ws + 6840320;              // 32,768
    float* by  = ws + 6873088;              // 128
    const long SL = 524288;                 // one [B][S][D] slice
    float* FTP = REG;
    float* PVP = REG;
    float* PM  = REG + 4 * SL;              // lives between ftp-death and pvp-birth
    float* PS  = PM + 65536;

    const float* adjBase  = graphs + (long)SS * SS;  // [:, TYPE_IDX=1]
    const float* biasBase = biases + (long)SS * SS;

    prep_wy<<<128, 256, 0, stream>>>(gc_w, gc_b, attn_w, Wy, by);

    const float* xin = inputs;
    for (int L = 0; L < NLAYERS; ++L) {
        // y = x @ Wy[L]   -> YFT
        gemm64<<<dim3(128, 1, 1), 256, 0, stream>>>(
            xin, 0, HH, Wy + (long)L * HH * DD, 0,
            nullptr, nullptr, YFT, 0, BB * SS, DD, HH, 0, 0);
        // ft partials = adj @ y  (split-K 8)
        ftp_gemm<<<dim3(32, 8, BB), 256, 0, stream>>>(adjBase, YFT, FTP);
        // ft = sum partials + b_y ; f = ft @ attn_a   (ft overwrites YFT)
        reduce_ft_f<<<2048, 256, 0, stream>>>(FTP, by + L * DD, attn_a + (long)L * DD, YFT, F);
        // column softmax stats
        col_stats_part<<<dim3(8, 8, BB), 256, 0, stream>>>(biasBase, F, PM, PS);
        col_stats_merge<<<32, 256, 0, stream>>>(PM, PS, Mv, Sv);
        // PV partials (split-J 8), then combine + leaky + tile + residual
        pvp_gemm<<<dim3(32, 8, BB), 256, 0, stream>>>(biasBase, F, Mv, Sv, YFT, PVP);
        pv_combine8<<<2048, 256, 0, stream>>>(PVP, xin, X);
        xin = X;
    }

    float* G  = REG;                 // 2,097,152
    float* H1 = REG + 2097152;       // 2,097,152
    layernorm_g<<<BB * SS, 256, 0, stream>>>(X, inputs, ln_a, ln_b, G);
    gemm64<<<dim3(128, 4, 1), 256, 0, stream>>>(
        G, 0, HH, w1, 0, w1b, nullptr, H1, 0, BB * SS, HH, HH, 1, 1);
    gemm64<<<dim3(128, 4, 1), 256, 0, stream>>>(
        H1, 0, HH, w2, 0, w2b, G, out, 0, BB * SS, HH, HH, 1, 0);
}

// Round 3
// 396.131 us; speedup vs baseline: 2.6993x; 1.2379x over previous
//
#include <hip/hip_runtime.h>
#include <math.h>

#define BB 4
#define SS 2048
#define HH 256
#define DD 64
#define NLAYERS 2
#define NCH 64   // i-split for column stats

__device__ __forceinline__ float lrelu(float v) { return v > 0.f ? v : 0.01f * v; }

// ---------------------------------------------------------------------------
// Generic f32 GEMM: C[M,N] = A[M,K] @ B (+bias[j]) (relu) (+res[i,j])
// transB=0: B is [K,N] row-major. transB=1: B is [N,K] row-major.
// 64x64 tile, K-chunk 32, 256 threads, 4x4 acc/thread.
// ---------------------------------------------------------------------------
__global__ __launch_bounds__(256) void gemm64(
    const float* __restrict__ A, long sAb, int lda,
    const float* __restrict__ Bm, long sBb,
    const float* __restrict__ bias,
    const float* __restrict__ res,
    float* __restrict__ C, long sCb,
    int M, int N, int K, int transB, int doRelu)
{
    __shared__ float As[32][68];
    __shared__ float Bs[32][68];
    const int b = blockIdx.z;
    const float* Ab = A + (long)b * sAb;
    const float* Bb = Bm + (long)b * sBb;
    float* Cb = C + (long)b * sCb;
    const int i0 = blockIdx.x * 64, j0 = blockIdx.y * 64;
    const int tid = threadIdx.x;
    const int tx = tid & 15, ty = tid >> 4;
    float acc[4][4] = {};

    for (int k0 = 0; k0 < K; k0 += 32) {
        {   // A tile 64x32 -> As[k][i]
            int c = tid & 31, r0 = tid >> 5;
            #pragma unroll
            for (int p = 0; p < 8; ++p) {
                int r = r0 + 8 * p;
                As[c][r] = Ab[(long)(i0 + r) * lda + (k0 + c)];
            }
        }
        if (!transB) {  // B tile 32x64 -> Bs[k][j]
            int c = tid & 63, r0 = tid >> 6;
            #pragma unroll
            for (int p = 0; p < 8; ++p) {
                int r = r0 + 4 * p;
                Bs[r][c] = Bb[(long)(k0 + r) * N + (j0 + c)];
            }
        } else {        // B is [N,K]: Bs[k][n] = B[n][k]
            int c = tid & 31, r0 = tid >> 5;
            #pragma unroll
            for (int p = 0; p < 8; ++p) {
                int n = r0 + 8 * p;
                Bs[c][n] = Bb[(long)(j0 + n) * K + (k0 + c)];
            }
        }
        __syncthreads();
        #pragma unroll
        for (int kk = 0; kk < 32; ++kk) {
            float4 a4 = *(const float4*)&As[kk][4 * ty];
            float4 b4 = *(const float4*)&Bs[kk][4 * tx];
            float av[4] = {a4.x, a4.y, a4.z, a4.w};
            float bv[4] = {b4.x, b4.y, b4.z, b4.w};
            #pragma unroll
            for (int r = 0; r < 4; ++r)
                #pragma unroll
                for (int cc = 0; cc < 4; ++cc)
                    acc[r][cc] += av[r] * bv[cc];
        }
        __syncthreads();
    }
    #pragma unroll
    for (int r = 0; r < 4; ++r) {
        int i = i0 + 4 * ty + r;
        #pragma unroll
        for (int cc = 0; cc < 4; ++cc) {
            int j = j0 + 4 * tx + cc;
            float v = acc[r][cc];
            if (bias) v += bias[j];
            if (doRelu) v = fmaxf(v, 0.f);
            if (res) v += res[(long)i * N + j];
            Cb[(long)i * N + j] = v;
        }
    }
}

// W_y[L][h][d] = sum_h' gc_w[L][h][h'] * attn_w[L][d][h'];  b_y[L][d] = gc_b[L]@attn_w[L][d]
__global__ __launch_bounds__(256) void prep_wy(
    const float* __restrict__ gc_w, const float* __restrict__ gc_b,
    const float* __restrict__ attn_w, float* __restrict__ Wy, float* __restrict__ by)
{
    int L = blockIdx.x >> 6, d = blockIdx.x & 63;
    int h = threadIdx.x;
    const float* gw = gc_w + (long)L * HH * HH;
    const float* aw = attn_w + (long)L * DD * HH + (long)d * HH;
    float acc = 0.f;
    for (int hp = 0; hp < HH; ++hp) acc += gw[(long)h * HH + hp] * aw[hp];
    Wy[((long)L * HH + h) * DD + d] = acc;
    if (h == 0) {
        float ba = 0.f;
        const float* gb = gc_b + (long)L * HH;
        for (int hp = 0; hp < HH; ++hp) ba += gb[hp] * aw[hp];
        by[L * DD + d] = ba;
    }
}

// FTP[ky][b][i][d] partial of adj@y over K-slice ky (256 k's each)
__global__ __launch_bounds__(256) void ftp_gemm(
    const float* __restrict__ adjB, const float* __restrict__ Y,
    float* __restrict__ FTP)
{
    __shared__ float As[32][68];   // [k][i]
    __shared__ float Bs[32][68];   // [k][d]
    const int b = blockIdx.z;
    const int i0 = blockIdx.x * 64;
    const int ky = blockIdx.y;
    const float* A = adjB + (long)b * 2 * SS * SS;
    const int tid = threadIdx.x;
    const int tx = tid & 15, ty = tid >> 4;
    float acc[4][4] = {};

    for (int kc = 0; kc < 256; kc += 32) {
        int k0 = ky * 256 + kc;
        {   // adj tile 64 x 32
            int c = tid & 31, r0 = tid >> 5;
            #pragma unroll
            for (int p = 0; p < 8; ++p) {
                int r = r0 + 8 * p;
                As[c][r] = A[(long)(i0 + r) * SS + (k0 + c)];
            }
        }
        {   // y tile 32 x 64
            int d = tid & 63, r0 = tid >> 6;
            #pragma unroll
            for (int p = 0; p < 8; ++p) {
                int r = r0 + 4 * p;
                Bs[r][d] = Y[((long)b * SS + k0 + r) * DD + d];
            }
        }
        __syncthreads();
        #pragma unroll
        for (int kk = 0; kk < 32; ++kk) {
            float4 a4 = *(const float4*)&As[kk][4 * ty];
            float4 b4 = *(const float4*)&Bs[kk][4 * tx];
            float av[4] = {a4.x, a4.y, a4.z, a4.w};
            float bv[4] = {b4.x, b4.y, b4.z, b4.w};
            #pragma unroll
            for (int r = 0; r < 4; ++r)
                #pragma unroll
                for (int cc = 0; cc < 4; ++cc)
                    acc[r][cc] += av[r] * bv[cc];
        }
        __syncthreads();
    }
    #pragma unroll
    for (int r = 0; r < 4; ++r) {
        long i = i0 + 4 * ty + r;
        float4 o = {acc[r][0], acc[r][1], acc[r][2], acc[r][3]};
        *(float4*)&FTP[(((long)ky * BB + b) * SS + i) * DD + 4 * tx] = o;
    }
}

// FT[row][d] = sum_ky FTP + b_y[d];  F[row] = FT[row][:]@attn_a
__global__ __launch_bounds__(256) void reduce_ft_f(
    const float* __restrict__ FTP, const float* __restrict__ byL,
    const float* __restrict__ aaL, float* __restrict__ FT, float* __restrict__ F)
{
    int row = blockIdx.x * 4 + (threadIdx.x >> 6);
    int d = threadIdx.x & 63;
    float v = byL[d];
    #pragma unroll
    for (int sk = 0; sk < 8; ++sk)
        v += FTP[((long)sk * BB * SS + row) * DD + d];
    FT[(long)row * DD + d] = v;
    float t = v * aaL[d];
    #pragma unroll
    for (int off = 32; off; off >>= 1) t += __shfl_down(t, off, 64);
    if (d == 0) F[row] = t;
}

// fmax[b] = max_i F[b,i]
__global__ __launch_bounds__(256) void f_max(
    const float* __restrict__ F, float* __restrict__ fmaxv)
{
    __shared__ float red[4];
    int b = blockIdx.x, t = threadIdx.x;
    float m = -1e30f;
    #pragma unroll
    for (int p = 0; p < 8; ++p) m = fmaxf(m, F[b * SS + p * 256 + t]);
    #pragma unroll
    for (int off = 32; off; off >>= 1) m = fmaxf(m, __shfl_down(m, off, 64));
    if ((t & 63) == 0) red[t >> 6] = m;
    __syncthreads();
    if (t == 0) {
        m = fmaxf(fmaxf(red[0], red[1]), fmaxf(red[2], red[3]));
        fmaxv[b] = m;
    }
}

// Column softmax sums with analytic bound M_j = lrelu(fmax_b + f_j) + 8.
// Branch-free, float4 bias loads, 4 independent exp accumulators per thread.
// grid (2, NCH, BB), 256 threads; thread covers 4 consecutive j, 32 i's.
__global__ __launch_bounds__(256) void col_stats_part(
    const float* __restrict__ biasb, const float* __restrict__ f,
    const float* __restrict__ fmaxv,
    float* __restrict__ partS, float* __restrict__ Mv)
{
    __shared__ float fs[SS / NCH];
    const int b = blockIdx.z;
    const int chunk = blockIdx.y;
    const int j0 = blockIdx.x * 1024 + threadIdx.x * 4;
    const float* bb = biasb + (long)b * 2 * SS * SS;
    const int ILEN = SS / NCH;
    const int ibase = chunk * ILEN;

    if (threadIdx.x < ILEN) fs[threadIdx.x] = f[b * SS + ibase + threadIdx.x];

    float fj[4], M[4], s[4] = {0.f, 0.f, 0.f, 0.f};
    const float fmx = fmaxv[b];
    #pragma unroll
    for (int q = 0; q < 4; ++q) {
        fj[q] = f[b * SS + j0 + q];
        M[q] = lrelu(fmx + fj[q]) + 8.f;
    }
    __syncthreads();

    for (int ii = 0; ii < ILEN; ii += 2) {
        float fi0 = fs[ii], fi1 = fs[ii + 1];
        float4 b0 = *(const float4*)&bb[(long)(ibase + ii) * SS + j0];
        float4 b1 = *(const float4*)&bb[(long)(ibase + ii + 1) * SS + j0];
        s[0] += __expf(lrelu(fi0 + fj[0]) + b0.x - M[0]);
        s[1] += __expf(lrelu(fi0 + fj[1]) + b0.y - M[1]);
        s[2] += __expf(lrelu(fi0 + fj[2]) + b0.z - M[2]);
        s[3] += __expf(lrelu(fi0 + fj[3]) + b0.w - M[3]);
        s[0] += __expf(lrelu(fi1 + fj[0]) + b1.x - M[0]);
        s[1] += __expf(lrelu(fi1 + fj[1]) + b1.y - M[1]);
        s[2] += __expf(lrelu(fi1 + fj[2]) + b1.z - M[2]);
        s[3] += __expf(lrelu(fi1 + fj[3]) + b1.w - M[3]);
    }
    #pragma unroll
    for (int q = 0; q < 4; ++q)
        partS[((long)chunk * BB + b) * SS + j0 + q] = s[q];
    if (chunk == 0) {
        #pragma unroll
        for (int q = 0; q < 4; ++q) Mv[b * SS + j0 + q] = M[q];
    }
}

__global__ __launch_bounds__(256) void col_stats_merge(
    const float* __restrict__ partS, float* __restrict__ Sinv)
{
    int idx = blockIdx.x * 256 + threadIdx.x;   // b*S + j
    int b = idx / SS, j = idx % SS;
    float s = 0.f;
    #pragma unroll
    for (int c = 0; c < NCH; ++c)
        s += partS[((long)c * BB + b) * SS + j];
    Sinv[idx] = 1.f / s;
}

// PVP[jy][b][i][d] = sum_{j in slice jy} w_ij * ft[j,d]
// w_ij = exp(lrelu(f_i+f_j)+bias[i,j] - M_j) * sinv_j
__global__ __launch_bounds__(256) void pvp_gemm(
    const float* __restrict__ biasb, const float* __restrict__ f,
    const float* __restrict__ Mv, const float* __restrict__ Sinv,
    const float* __restrict__ FT, float* __restrict__ PVP)
{
    __shared__ float fts[32][68];
    __shared__ float wlds[64][36];
    const int b = blockIdx.z;
    const int i0 = blockIdx.x * 64;
    const int jy = blockIdx.y;
    const float* bb = biasb + (long)b * 2 * SS * SS;
    const int tid = threadIdx.x;
    const int tx = tid & 15, ty = tid >> 4;
    float acc[4][4] = {};

    for (int jc = 0; jc < 256; jc += 32) {
        int j0 = jy * 256 + jc;
        #pragma unroll
        for (int p = 0; p < 2; ++p) {  // stage ft[j0:j0+32, 0:64]
            int q = tid + 256 * p;
            int jj = q >> 4, dd = (q & 15) << 2;
            *(float4*)&fts[jj][dd] =
                *(const float4*)&FT[((long)(b * SS + j0 + jj)) * DD + dd];
        }
        {   // w tile 64 x 32
            int jl = tid & 31, il0 = tid >> 5;
            int j = j0 + jl;
            float fj = f[b * SS + j];
            float mj = Mv[b * SS + j];
            float sj = Sinv[b * SS + j];
            #pragma unroll
            for (int p = 0; p < 8; ++p) {
                int il = il0 + 8 * p;
                int i = i0 + il;
                float l = lrelu(f[b * SS + i] + fj) + bb[(long)i * SS + j];
                wlds[il][jl] = __expf(l - mj) * sj;
            }
        }
        __syncthreads();
        #pragma unroll
        for (int jj4 = 0; jj4 < 32; jj4 += 4) {
            float fvv[4][4];
            #pragma unroll
            for (int t = 0; t < 4; ++t) {
                float4 fv = *(const float4*)&fts[jj4 + t][4 * tx];
                fvv[t][0] = fv.x; fvv[t][1] = fv.y; fvv[t][2] = fv.z; fvv[t][3] = fv.w;
            }
            #pragma unroll
            for (int r = 0; r < 4; ++r) {
                float4 wv = *(const float4*)&wlds[4 * ty + r][jj4];
                float wr[4] = {wv.x, wv.y, wv.z, wv.w};
                #pragma unroll
                for (int t = 0; t < 4; ++t)
                    #pragma unroll
                    for (int cc = 0; cc < 4; ++cc)
                        acc[r][cc] += wr[t] * fvv[t][cc];
            }
        }
        __syncthreads();
    }
    #pragma unroll
    for (int r = 0; r < 4; ++r) {
        long i = i0 + 4 * ty + r;
        float4 o = {acc[r][0], acc[r][1], acc[r][2], acc[r][3]};
        *(float4*)&PVP[(((long)jy * BB + b) * SS + i) * DD + 4 * tx] = o;
    }
}

// x_out = tile(lrelu(sum_jy PVP), HEADS) + x_in
__global__ __launch_bounds__(256) void pv_combine8(
    const float* __restrict__ PVP, const float* __restrict__ xin, float* __restrict__ xout)
{
    int row = blockIdx.x * 4 + (threadIdx.x >> 6);
    int d = threadIdx.x & 63;
    float v = 0.f;
    #pragma unroll
    for (int jy = 0; jy < 8; ++jy)
        v += PVP[((long)jy * BB * SS + row) * DD + d];
    v = lrelu(v);
    #pragma unroll
    for (int rep = 0; rep < 4; ++rep) {
        long off = (long)row * HH + rep * DD + d;
        xout[off] = v + xin[off];
    }
}

// g = ln_a*(x-mean)/(std_ddof1 + eps) + ln_b + x0     (block = one row of 256)
__global__ __launch_bounds__(256) void layernorm_g(
    const float* __restrict__ x, const float* __restrict__ x0,
    const float* __restrict__ lna, const float* __restrict__ lnb,
    float* __restrict__ g)
{
    __shared__ float red[8];
    long row = blockIdx.x;
    int t = threadIdx.x;
    int wave = t >> 6, lane = t & 63;
    float v = x[row * HH + t];

    float sum = v;
    #pragma unroll
    for (int off = 32; off; off >>= 1) sum += __shfl_down(sum, off, 64);
    if (lane == 0) red[wave] = sum;
    __syncthreads();
    if (t < 64) {
        float s = (lane < 4) ? red[lane] : 0.f;
        s += __shfl_down(s, 2, 64);
        s += __shfl_down(s, 1, 64);
        if (lane == 0) red[4] = s / HH;
    }
    __syncthreads();
    float mean = red[4];
    float d = v - mean;
    float sq = d * d;
    #pragma unroll
    for (int off = 32; off; off >>= 1) sq += __shfl_down(sq, off, 64);
    __syncthreads();
    if (lane == 0) red[wave] = sq;
    __syncthreads();
    if (t < 64) {
        float s = (lane < 4) ? red[lane] : 0.f;
        s += __shfl_down(s, 2, 64);
        s += __shfl_down(s, 1, 64);
        if (lane == 0) red[5] = sqrtf(s / (HH - 1));
    }
    __syncthreads();
    float stdv = red[5];
    g[row * HH + t] = lna[t] * d / (stdv + 1e-6f) + lnb[t] + x0[row * HH + t];
}

extern "C" void kernel_launch(void* const* d_in, const int* in_sizes, int n_in,
                              void* d_out, int out_size, void* d_ws, size_t ws_size,
                              hipStream_t stream)
{
    const float* inputs = (const float*)d_in[0];
    const float* graphs = (const float*)d_in[1];
    const float* biases = (const float*)d_in[2];
    const float* gc_w   = (const float*)d_in[3];
    const float* gc_b   = (const float*)d_in[4];
    const float* attn_w = (const float*)d_in[5];
    const float* attn_a = (const float*)d_in[6];
    const float* ln_a   = (const float*)d_in[7];
    const float* ln_b   = (const float*)d_in[8];
    const float* w1     = (const float*)d_in[9];
    const float* w1b    = (const float*)d_in[10];
    const float* w2     = (const float*)d_in[11];
    const float* w2b    = (const float*)d_in[12];
    float* out = (float*)d_out;

    // ---- workspace layout (floats) ----
    float* ws  = (float*)d_ws;
    float* X   = ws;                        // 2,097,152
    float* REG = ws + 2097152;              // 4,194,304: FTP[0:8]/PVP[0:8]; partS overlays slices 4..7
    float* YFT = ws + 6291456;              // 524,288 (y, then ft)
    float* F   = ws + 6815744;              // 8,192
    float* Mv  = ws + 6823936;              // 8,192
    float* Sv  = ws + 6832128;              // 8,192
    float* Wy  = ws + 6840320;              // 32,768
    float* by  = ws + 6873088;              // 128
    float* FMX = ws + 6873216;              // 4
    const long SL = 524288;                 // one [B][S][D] slice
    float* FTP = REG;
    float* PVP = REG;
    float* PTS = REG + 4 * SL;              // NCH*BB*SS = 524,288 (FTP dead by then)

    const float* adjBase  = graphs + (long)SS * SS;  // [:, TYPE_IDX=1]
    const float* biasBase = biases + (long)SS * SS;

    prep_wy<<<128, 256, 0, stream>>>(gc_w, gc_b, attn_w, Wy, by);

    const float* xin = inputs;
    for (int L = 0; L < NLAYERS; ++L) {
        // y = x @ Wy[L]   -> YFT
        gemm64<<<dim3(128, 1, 1), 256, 0, stream>>>(
            xin, 0, HH, Wy + (long)L * HH * DD, 0,
            nullptr, nullptr, YFT, 0, BB * SS, DD, HH, 0, 0);
        // ft partials = adj @ y  (split-K 8)
        ftp_gemm<<<dim3(32, 8, BB), 256, 0, stream>>>(adjBase, YFT, FTP);
        // ft = sum partials + b_y ; f = ft @ attn_a   (ft overwrites YFT)
        reduce_ft_f<<<2048, 256, 0, stream>>>(FTP, by + L * DD, attn_a + (long)L * DD, YFT, F);
        f_max<<<BB, 256, 0, stream>>>(F, FMX);
        // column softmax sums (branch-free, bound M_j)
        col_stats_part<<<dim3(2, NCH, BB), 256, 0, stream>>>(biasBase, F, FMX, PTS, Mv);
        col_stats_merge<<<32, 256, 0, stream>>>(PTS, Sv);
        // PV partials (split-J 8), then combine + leaky + tile + residual
        pvp_gemm<<<dim3(32, 8, BB), 256, 0, stream>>>(biasBase, F, Mv, Sv, YFT, PVP);
        pv_combine8<<<2048, 256, 0, stream>>>(PVP, xin, X);
        xin = X;
    }

    float* G  = REG;                 // 2,097,152
    float* H1 = REG + 2097152;       // 2,097,152
    layernorm_g<<<BB * SS, 256, 0, stream>>>(X, inputs, ln_a, ln_b, G);
    gemm64<<<dim3(128, 4, 1), 256, 0, stream>>>(
        G, 0, HH, w1, 0, w1b, nullptr, H1, 0, BB * SS, HH, HH, 1, 1);
    gemm64<<<dim3(128, 4, 1), 256, 0, stream>>>(
        H1, 0, HH, w2, 0, w2b, G, out, 0, BB * SS, HH, HH, 1, 0);
}

// Round 5
// 374.599 us; speedup vs baseline: 2.8545x; 1.0575x over previous
//
#include <hip/hip_runtime.h>
#include <math.h>

#define BB 4
#define SS 2048
#define HH 256
#define DD 64
#define NLAYERS 2
#define NCH 64       // i-split for column stats
#define NKY 4        // split-K for ftp
#define NJY 4        // split-J for pvp
#define KSL (SS/NKY) // 512
#define JSL (SS/NJY) // 512

// static scales to keep f16 hi/lo splits in range (layer-2 values can be ~1e4-1e5)
#define YSC  (1.f/64.f)    // y stored as y/64
#define YSCI 64.f
#define FSC  (1.f/256.f)   // ft stored as ft/256
#define WSC  256.f         // W stored as 256*W  (256 * 1/256 = 1 in the product)

typedef _Float16 f16;
typedef f16 half8 __attribute__((ext_vector_type(8)));
typedef float f32x4 __attribute__((ext_vector_type(4)));
#define MFMA16(a, b, c) __builtin_amdgcn_mfma_f32_16x16x32_f16(a, b, c, 0, 0, 0)

__device__ __forceinline__ float lrelu(float v) { return v > 0.f ? v : 0.01f * v; }

// ---------------------------------------------------------------------------
// Generic f32 GEMM (FFN tail): C[M,N]=A@B (+bias)(relu)(+res). 64x64 tile.
// ---------------------------------------------------------------------------
__global__ __launch_bounds__(256) void gemm64(
    const float* __restrict__ A, long sAb, int lda,
    const float* __restrict__ Bm, long sBb,
    const float* __restrict__ bias,
    const float* __restrict__ res,
    float* __restrict__ C, long sCb,
    int M, int N, int K, int transB, int doRelu)
{
    __shared__ float As[32][68];
    __shared__ float Bs[32][68];
    const int b = blockIdx.z;
    const float* Ab = A + (long)b * sAb;
    const float* Bb = Bm + (long)b * sBb;
    float* Cb = C + (long)b * sCb;
    const int i0 = blockIdx.x * 64, j0 = blockIdx.y * 64;
    const int tid = threadIdx.x;
    const int tx = tid & 15, ty = tid >> 4;
    float acc[4][4] = {};

    for (int k0 = 0; k0 < K; k0 += 32) {
        {
            int c = tid & 31, r0 = tid >> 5;
            #pragma unroll
            for (int p = 0; p < 8; ++p) {
                int r = r0 + 8 * p;
                As[c][r] = Ab[(long)(i0 + r) * lda + (k0 + c)];
            }
        }
        if (!transB) {
            int c = tid & 63, r0 = tid >> 6;
            #pragma unroll
            for (int p = 0; p < 8; ++p) {
                int r = r0 + 4 * p;
                Bs[r][c] = Bb[(long)(k0 + r) * N + (j0 + c)];
            }
        } else {
            int c = tid & 31, r0 = tid >> 5;
            #pragma unroll
            for (int p = 0; p < 8; ++p) {
                int n = r0 + 8 * p;
                Bs[c][n] = Bb[(long)(j0 + n) * K + (k0 + c)];
            }
        }
        __syncthreads();
        #pragma unroll
        for (int kk = 0; kk < 32; ++kk) {
            float4 a4 = *(const float4*)&As[kk][4 * ty];
            float4 b4 = *(const float4*)&Bs[kk][4 * tx];
            float av[4] = {a4.x, a4.y, a4.z, a4.w};
            float bv[4] = {b4.x, b4.y, b4.z, b4.w};
            #pragma unroll
            for (int r = 0; r < 4; ++r)
                #pragma unroll
                for (int cc = 0; cc < 4; ++cc)
                    acc[r][cc] += av[r] * bv[cc];
        }
        __syncthreads();
    }
    #pragma unroll
    for (int r = 0; r < 4; ++r) {
        int i = i0 + 4 * ty + r;
        #pragma unroll
        for (int cc = 0; cc < 4; ++cc) {
            int j = j0 + 4 * tx + cc;
            float v = acc[r][cc];
            if (bias) v += bias[j];
            if (doRelu) v = fmaxf(v, 0.f);
            if (res) v += res[(long)i * N + j];
            Cb[(long)i * N + j] = v;
        }
    }
}

// W_y[L][h][d] = gc_w[L] @ attn_w[L]^T;  b_y[L][d] = gc_b[L] @ attn_w[L][d]
__global__ __launch_bounds__(256) void prep_wy(
    const float* __restrict__ gc_w, const float* __restrict__ gc_b,
    const float* __restrict__ attn_w, float* __restrict__ Wy, float* __restrict__ by)
{
    int L = blockIdx.x >> 6, d = blockIdx.x & 63;
    int h = threadIdx.x;
    const float* gw = gc_w + (long)L * HH * HH;
    const float* aw = attn_w + (long)L * DD * HH + (long)d * HH;
    float acc = 0.f;
    for (int hp = 0; hp < HH; ++hp) acc += gw[(long)h * HH + hp] * aw[hp];
    Wy[((long)L * HH + h) * DD + d] = acc;
    if (h == 0) {
        float ba = 0.f;
        const float* gb = gc_b + (long)L * HH;
        for (int hp = 0; hp < HH; ++hp) ba += gb[hp] * aw[hp];
        by[L * DD + d] = ba;
    }
}

// y = x @ Wy[L]  -> written TRANSPOSED f16 hi/lo of y*YSC: yT[b][d][s]
__global__ __launch_bounds__(256) void y_gemm_t(
    const float* __restrict__ xin, const float* __restrict__ WyL,
    f16* __restrict__ yTh, f16* __restrict__ yTl)
{
    __shared__ float Ls[64][68];
    const int blk = blockIdx.x;
    const int b = blk >> 5, st = blk & 31;
    const long row0 = (long)b * SS + st * 64;
    const int tid = threadIdx.x;
    const int tx = tid & 15, ty = tid >> 4;
    float acc[4][4] = {};

    for (int k0 = 0; k0 < HH; k0 += 32) {
        {   // A tile 64x32 -> Ls[k][i] (rows 0-31)
            int c = tid & 31, r0 = tid >> 5;
            #pragma unroll
            for (int p = 0; p < 8; ++p) {
                int r = r0 + 8 * p;
                Ls[c][r] = xin[(row0 + r) * HH + k0 + c];
            }
        }
        {   // B tile 32x64 -> Ls[32+k][d]
            int c = tid & 63, r0 = tid >> 6;
            #pragma unroll
            for (int p = 0; p < 8; ++p) {
                int r = r0 + 4 * p;
                Ls[32 + r][c] = WyL[(long)(k0 + r) * DD + c];
            }
        }
        __syncthreads();
        #pragma unroll
        for (int kk = 0; kk < 32; ++kk) {
            float4 a4 = *(const float4*)&Ls[kk][4 * ty];
            float4 b4 = *(const float4*)&Ls[32 + kk][4 * tx];
            float av[4] = {a4.x, a4.y, a4.z, a4.w};
            float bv[4] = {b4.x, b4.y, b4.z, b4.w};
            #pragma unroll
            for (int r = 0; r < 4; ++r)
                #pragma unroll
                for (int cc = 0; cc < 4; ++cc)
                    acc[r][cc] += av[r] * bv[cc];
        }
        __syncthreads();
    }
    #pragma unroll
    for (int r = 0; r < 4; ++r)
        #pragma unroll
        for (int cc = 0; cc < 4; ++cc)
            Ls[4 * ty + r][4 * tx + cc] = acc[r][cc];
    __syncthreads();
    int d = tid >> 2, sq = (tid & 3) * 16;
    long obase = ((long)b * DD + d) * SS + st * 64 + sq;
    half8 h0, l0, h1, l1;
    #pragma unroll
    for (int e = 0; e < 8; ++e) {
        float v = Ls[sq + e][d] * YSC;
        f16 h = (f16)v; h0[e] = h; l0[e] = (f16)((v - (float)h) * 2048.f);
        float v2 = Ls[sq + 8 + e][d] * YSC;
        f16 h2 = (f16)v2; h1[e] = h2; l1[e] = (f16)((v2 - (float)h2) * 2048.f);
    }
    *(half8*)(yTh + obase) = h0; *(half8*)(yTh + obase + 8) = h1;
    *(half8*)(yTl + obase) = l0; *(half8*)(yTl + obase + 8) = l1;
}

// FTP[ky][b][i][d] = adj[i, kslice] @ y[kslice, d]   (MFMA, f16 hi/lo split)
__global__ __launch_bounds__(256) void ftp_mfma(
    const float* __restrict__ adjB,
    const f16* __restrict__ yTh, const f16* __restrict__ yTl,
    float* __restrict__ FTP)
{
    const int b = blockIdx.z;
    const int i0 = blockIdx.x * 64;
    const int ky = blockIdx.y;
    const int tid = threadIdx.x;
    const int w = tid >> 6, l = tid & 63;
    const int lr = l & 15, kg = (l >> 4) * 8;
    const float* Arow = adjB + (long)b * 2 * SS * SS + (long)(i0 + w * 16 + lr) * SS;
    const f16* Bh = yTh + ((long)b * DD + lr) * SS;
    const f16* Bl = yTl + ((long)b * DD + lr) * SS;

    f32x4 acc_h[4] = {}; f32x4 acc_m[4] = {};
    for (int ks = 0; ks < KSL; ks += 32) {
        int k = ky * KSL + ks + kg;
        half8 ah, al;
        {
            float4 a0 = *(const float4*)(Arow + k);
            float4 a1 = *(const float4*)(Arow + k + 4);
            float av[8] = {a0.x, a0.y, a0.z, a0.w, a1.x, a1.y, a1.z, a1.w};
            #pragma unroll
            for (int e = 0; e < 8; ++e) {
                f16 h = (f16)av[e]; ah[e] = h;
                al[e] = (f16)((av[e] - (float)h) * 2048.f);
            }
        }
        #pragma unroll
        for (int dt = 0; dt < 4; ++dt) {
            long off = (long)dt * 16 * SS + k;
            half8 bh = *(const half8*)(Bh + off);
            half8 bl = *(const half8*)(Bl + off);
            acc_h[dt] = MFMA16(ah, bh, acc_h[dt]);
            acc_m[dt] = MFMA16(ah, bl, acc_m[dt]);
            acc_m[dt] = MFMA16(al, bh, acc_m[dt]);
        }
    }
    const int rg0 = (l >> 4) * 4;
    #pragma unroll
    for (int dt = 0; dt < 4; ++dt)
        #pragma unroll
        for (int rr = 0; rr < 4; ++rr) {
            long iD = i0 + w * 16 + rg0 + rr;
            FTP[(((long)ky * BB + b) * SS + iD) * DD + dt * 16 + lr] =
                (acc_h[dt][rr] + acc_m[dt][rr] * (1.f / 2048.f)) * YSCI;
        }
}

// ft = sum_ky FTP + b_y; F = ft @ attn_a; write ft transposed f16 hi/lo of ft*FSC
__global__ __launch_bounds__(256) void reduce_ft_t(
    const float* __restrict__ FTP, const float* __restrict__ byL,
    const float* __restrict__ aaL, float* __restrict__ F,
    f16* __restrict__ fTh, f16* __restrict__ fTl)
{
    __shared__ float Ls[64][68];
    const int blk = blockIdx.x;
    const int b = blk >> 5, st = blk & 31;
    const int s0 = st * 64;
    const int tid = threadIdx.x;
    {
        int c4 = (tid & 15) * 4, r0 = tid >> 4;
        float4 bb4 = *(const float4*)&byL[c4];
        #pragma unroll
        for (int p = 0; p < 4; ++p) {
            int r = r0 + 16 * p;
            long rowoff = ((long)b * SS + s0 + r) * DD + c4;
            float4 v = *(const float4*)&FTP[rowoff];
            #pragma unroll
            for (int ky = 1; ky < NKY; ++ky) {
                float4 u = *(const float4*)&FTP[(long)ky * BB * SS * DD + rowoff];
                v.x += u.x; v.y += u.y; v.z += u.z; v.w += u.w;
            }
            v.x += bb4.x; v.y += bb4.y; v.z += bb4.z; v.w += bb4.w;
            *(float4*)&Ls[r][c4] = v;
        }
    }
    __syncthreads();
    {   // F[row] = ft @ attn_a
        int r = tid >> 2, q = tid & 3;
        float dot = 0.f;
        #pragma unroll
        for (int e = 0; e < 16; ++e) dot += Ls[r][q * 16 + e] * aaL[q * 16 + e];
        dot += __shfl_xor(dot, 1, 64);
        dot += __shfl_xor(dot, 2, 64);
        if (q == 0) F[b * SS + s0 + r] = dot;
    }
    int d = tid >> 2, sq = (tid & 3) * 16;
    long obase = ((long)b * DD + d) * SS + s0 + sq;
    half8 h0, l0, h1, l1;
    #pragma unroll
    for (int e = 0; e < 8; ++e) {
        float v = Ls[sq + e][d] * FSC;
        f16 h = (f16)v; h0[e] = h; l0[e] = (f16)((v - (float)h) * 2048.f);
        float v2 = Ls[sq + 8 + e][d] * FSC;
        f16 h2 = (f16)v2; h1[e] = h2; l1[e] = (f16)((v2 - (float)h2) * 2048.f);
    }
    *(half8*)(fTh + obase) = h0; *(half8*)(fTh + obase + 8) = h1;
    *(half8*)(fTl + obase) = l0; *(half8*)(fTl + obase + 8) = l1;
}

// fmax[b] = max_i F[b,i]
__global__ __launch_bounds__(256) void f_max(
    const float* __restrict__ F, float* __restrict__ fmaxv)
{
    __shared__ float red[4];
    int b = blockIdx.x, t = threadIdx.x;
    float m = -1e30f;
    #pragma unroll
    for (int p = 0; p < 8; ++p) m = fmaxf(m, F[b * SS + p * 256 + t]);
    #pragma unroll
    for (int off = 32; off; off >>= 1) m = fmaxf(m, __shfl_down(m, off, 64));
    if ((t & 63) == 0) red[t >> 6] = m;
    __syncthreads();
    if (t == 0) fmaxv[b] = fmaxf(fmaxf(red[0], red[1]), fmaxf(red[2], red[3]));
}

// Column softmax sums with analytic bound M_j = lrelu(fmax_b + f_j) + 8.
__global__ __launch_bounds__(256) void col_stats_part(
    const float* __restrict__ biasb, const float* __restrict__ f,
    const float* __restrict__ fmaxv,
    float* __restrict__ partS, float* __restrict__ Mv)
{
    __shared__ float fs[SS / NCH];
    const int b = blockIdx.z;
    const int chunk = blockIdx.y;
    const int j0 = blockIdx.x * 1024 + threadIdx.x * 4;
    const float* bb = biasb + (long)b * 2 * SS * SS;
    const int ILEN = SS / NCH;
    const int ibase = chunk * ILEN;

    if (threadIdx.x < ILEN) fs[threadIdx.x] = f[b * SS + ibase + threadIdx.x];

    float fj[4], M[4], s[4] = {0.f, 0.f, 0.f, 0.f};
    const float fmx = fmaxv[b];
    #pragma unroll
    for (int q = 0; q < 4; ++q) {
        fj[q] = f[b * SS + j0 + q];
        M[q] = lrelu(fmx + fj[q]) + 8.f;
    }
    __syncthreads();

    for (int ii = 0; ii < ILEN; ii += 2) {
        float fi0 = fs[ii], fi1 = fs[ii + 1];
        float4 b0 = *(const float4*)&bb[(long)(ibase + ii) * SS + j0];
        float4 b1 = *(const float4*)&bb[(long)(ibase + ii + 1) * SS + j0];
        s[0] += __expf(lrelu(fi0 + fj[0]) + b0.x - M[0]);
        s[1] += __expf(lrelu(fi0 + fj[1]) + b0.y - M[1]);
        s[2] += __expf(lrelu(fi0 + fj[2]) + b0.z - M[2]);
        s[3] += __expf(lrelu(fi0 + fj[3]) + b0.w - M[3]);
        s[0] += __expf(lrelu(fi1 + fj[0]) + b1.x - M[0]);
        s[1] += __expf(lrelu(fi1 + fj[1]) + b1.y - M[1]);
        s[2] += __expf(lrelu(fi1 + fj[2]) + b1.z - M[2]);
        s[3] += __expf(lrelu(fi1 + fj[3]) + b1.w - M[3]);
    }
    #pragma unroll
    for (int q = 0; q < 4; ++q)
        partS[((long)chunk * BB + b) * SS + j0 + q] = s[q];
    if (chunk == 0) {
        #pragma unroll
        for (int q = 0; q < 4; ++q) Mv[b * SS + j0 + q] = M[q];
    }
}

__global__ __launch_bounds__(256) void col_stats_merge(
    const float* __restrict__ partS, float* __restrict__ Sinv)
{
    int idx = blockIdx.x * 256 + threadIdx.x;
    int b = idx / SS, j = idx % SS;
    float s = 0.f;
    #pragma unroll
    for (int c = 0; c < NCH; ++c)
        s += partS[((long)c * BB + b) * SS + j];
    Sinv[idx] = 1.f / s;
}

// PVP[jy][b][i][d] = sum_{j in slice} W_ij * ft[j,d]   (MFMA, f16 split)
__global__ __launch_bounds__(256) void pvp_mfma(
    const float* __restrict__ biasb, const float* __restrict__ f,
    const float* __restrict__ Mv, const float* __restrict__ Sinv,
    const f16* __restrict__ fTh, const f16* __restrict__ fTl,
    float* __restrict__ PVP)
{
    __shared__ float Wt[64][36];
    __shared__ float fi_s[64];
    const int b = blockIdx.z;
    const int i0 = blockIdx.x * 64;
    const int jy = blockIdx.y;
    const float* bb = biasb + (long)b * 2 * SS * SS;
    const int tid = threadIdx.x;
    const int w = tid >> 6, l = tid & 63;
    const int lr = l & 15, kg = (l >> 4) * 8;
    const f16* Bh = fTh + ((long)b * DD + lr) * SS;
    const f16* Bl = fTl + ((long)b * DD + lr) * SS;

    if (tid < 64) fi_s[tid] = f[b * SS + i0 + tid];
    __syncthreads();

    f32x4 acc_h[4] = {}; f32x4 acc_m[4] = {};
    for (int jc = 0; jc < JSL; jc += 32) {
        int j0 = jy * JSL + jc;
        {   // W tile 64 x 32 (stored as 256*W for f16-normal range)
            int jl = tid & 31, il0 = tid >> 5;
            int j = j0 + jl;
            float fj = f[b * SS + j];
            float mj = Mv[b * SS + j];
            float sj = Sinv[b * SS + j];
            #pragma unroll
            for (int p = 0; p < 8; ++p) {
                int il = il0 + 8 * p;
                float lgt = lrelu(fi_s[il] + fj) + bb[(long)(i0 + il) * SS + j];
                Wt[il][jl] = __expf(lgt - mj) * sj * WSC;
            }
        }
        __syncthreads();
        half8 ah, al;
        {
            const int rw = w * 16 + lr;
            #pragma unroll
            for (int e = 0; e < 8; ++e) {
                float v = Wt[rw][kg + e];
                f16 h = (f16)v; ah[e] = h;
                al[e] = (f16)((v - (float)h) * 2048.f);
            }
        }
        #pragma unroll
        for (int dt = 0; dt < 4; ++dt) {
            long off = (long)dt * 16 * SS + j0 + kg;
            half8 bh = *(const half8*)(Bh + off);
            half8 bl = *(const half8*)(Bl + off);
            acc_h[dt] = MFMA16(ah, bh, acc_h[dt]);
            acc_m[dt] = MFMA16(ah, bl, acc_m[dt]);
            acc_m[dt] = MFMA16(al, bh, acc_m[dt]);
        }
        __syncthreads();
    }
    const int rg0 = (l >> 4) * 4;
    #pragma unroll
    for (int dt = 0; dt < 4; ++dt)
        #pragma unroll
        for (int rr = 0; rr < 4; ++rr) {
            long iD = i0 + w * 16 + rg0 + rr;
            PVP[(((long)jy * BB + b) * SS + iD) * DD + dt * 16 + lr] =
                acc_h[dt][rr] + acc_m[dt][rr] * (1.f / 2048.f);   // WSC*FSC = 1
        }
}

// x_out = tile(lrelu(sum_jy PVP), HEADS) + x_in
__global__ __launch_bounds__(256) void pv_combine4(
    const float* __restrict__ PVP, const float* __restrict__ xin, float* __restrict__ xout)
{
    int row = blockIdx.x * 4 + (threadIdx.x >> 6);
    int d = threadIdx.x & 63;
    float v = 0.f;
    #pragma unroll
    for (int jy = 0; jy < NJY; ++jy)
        v += PVP[((long)jy * BB * SS + row) * DD + d];
    v = lrelu(v);
    #pragma unroll
    for (int rep = 0; rep < 4; ++rep) {
        long off = (long)row * HH + rep * DD + d;
        xout[off] = v + xin[off];
    }
}

// g = ln_a*(x-mean)/(std_ddof1 + eps) + ln_b + x0
__global__ __launch_bounds__(256) void layernorm_g(
    const float* __restrict__ x, const float* __restrict__ x0,
    const float* __restrict__ lna, const float* __restrict__ lnb,
    float* __restrict__ g)
{
    __shared__ float red[8];
    long row = blockIdx.x;
    int t = threadIdx.x;
    int wave = t >> 6, lane = t & 63;
    float v = x[row * HH + t];

    float sum = v;
    #pragma unroll
    for (int off = 32; off; off >>= 1) sum += __shfl_down(sum, off, 64);
    if (lane == 0) red[wave] = sum;
    __syncthreads();
    if (t < 64) {
        float s = (lane < 4) ? red[lane] : 0.f;
        s += __shfl_down(s, 2, 64);
        s += __shfl_down(s, 1, 64);
        if (lane == 0) red[4] = s / HH;
    }
    __syncthreads();
    float mean = red[4];
    float d = v - mean;
    float sq = d * d;
    #pragma unroll
    for (int off = 32; off; off >>= 1) sq += __shfl_down(sq, off, 64);
    __syncthreads();
    if (lane == 0) red[wave] = sq;
    __syncthreads();
    if (t < 64) {
        float s = (lane < 4) ? red[lane] : 0.f;
        s += __shfl_down(s, 2, 64);
        s += __shfl_down(s, 1, 64);
        if (lane == 0) red[5] = sqrtf(s / (HH - 1));
    }
    __syncthreads();
    float stdv = red[5];
    g[row * HH + t] = lna[t] * d / (stdv + 1e-6f) + lnb[t] + x0[row * HH + t];
}

extern "C" void kernel_launch(void* const* d_in, const int* in_sizes, int n_in,
                              void* d_out, int out_size, void* d_ws, size_t ws_size,
                              hipStream_t stream)
{
    const float* inputs = (const float*)d_in[0];
    const float* graphs = (const float*)d_in[1];
    const float* biases = (const float*)d_in[2];
    const float* gc_w   = (const float*)d_in[3];
    const float* gc_b   = (const float*)d_in[4];
    const float* attn_w = (const float*)d_in[5];
    const float* attn_a = (const float*)d_in[6];
    const float* ln_a   = (const float*)d_in[7];
    const float* ln_b   = (const float*)d_in[8];
    const float* w1     = (const float*)d_in[9];
    const float* w1b    = (const float*)d_in[10];
    const float* w2     = (const float*)d_in[11];
    const float* w2b    = (const float*)d_in[12];
    float* out = (float*)d_out;

    // ---- workspace layout (floats) ----
    float* ws  = (float*)d_ws;
    float* X   = ws;                         // 2,097,152
    float* REG = ws + 2097152;               // 4,194,304
    float* F   = ws + 6291456;               // 8,192
    float* Mv  = ws + 6299648;               // 8,192
    float* Sv  = ws + 6307840;               // 8,192
    float* Wy  = ws + 6316032;               // 32,768
    float* by  = ws + 6348800;               // 128
    float* FMX = ws + 6348928;               // 4 (pad to 128)
    f16* yTh   = (f16*)(ws + 6349056);       // 524,288 halves = 262,144 floats
    f16* yTl   = (f16*)(ws + 6611200);
    f16* fTh   = (f16*)(ws + 6873344);
    f16* fTl   = (f16*)(ws + 7135488);       // end 7,397,632 floats (~29.6 MB)

    float* FTP = REG;                        // NKY slices (2,097,152)
    float* PVP = REG;                        // NJY slices (2,097,152)
    float* PTS = REG + 2097152;              // NCH*BB*SS = 524,288

    const float* adjBase  = graphs + (long)SS * SS;  // [:, TYPE_IDX=1]
    const float* biasBase = biases + (long)SS * SS;

    prep_wy<<<128, 256, 0, stream>>>(gc_w, gc_b, attn_w, Wy, by);

    const float* xin = inputs;
    for (int L = 0; L < NLAYERS; ++L) {
        y_gemm_t<<<128, 256, 0, stream>>>(xin, Wy + (long)L * HH * DD, yTh, yTl);
        ftp_mfma<<<dim3(32, NKY, BB), 256, 0, stream>>>(adjBase, yTh, yTl, FTP);
        reduce_ft_t<<<128, 256, 0, stream>>>(FTP, by + L * DD, attn_a + (long)L * DD,
                                             F, fTh, fTl);
        f_max<<<BB, 256, 0, stream>>>(F, FMX);
        col_stats_part<<<dim3(2, NCH, BB), 256, 0, stream>>>(biasBase, F, FMX, PTS, Mv);
        col_stats_merge<<<32, 256, 0, stream>>>(PTS, Sv);
        pvp_mfma<<<dim3(32, NJY, BB), 256, 0, stream>>>(biasBase, F, Mv, Sv, fTh, fTl, PVP);
        pv_combine4<<<2048, 256, 0, stream>>>(PVP, xin, X);
        xin = X;
    }

    float* G  = REG;
    float* H1 = REG + 2097152;
    layernorm_g<<<BB * SS, 256, 0, stream>>>(X, inputs, ln_a, ln_b, G);
    gemm64<<<dim3(128, 4, 1), 256, 0, stream>>>(
        G, 0, HH, w1, 0, w1b, nullptr, H1, 0, BB * SS, HH, HH, 1, 1);
    gemm64<<<dim3(128, 4, 1), 256, 0, stream>>>(
        H1, 0, HH, w2, 0, w2b, G, out, 0, BB * SS, HH, HH, 1, 0);
}

// Round 6
// 371.686 us; speedup vs baseline: 2.8769x; 1.0078x over previous
//
#include <hip/hip_runtime.h>
#include <math.h>

#define BB 4
#define SS 2048
#define HH 256
#define DD 64
#define NLAYERS 2
#define NCH 64        // i-split for column stats
#define NKY 8         // split-K for ftp
#define NJY 8         // split-J for pvp
#define KSL (SS/NKY)  // 256
#define JSL (SS/NJY)  // 256

// static scales for f16 hi/lo splits (layer-2 activations are large)
#define XSC  (1.f/64.f)   // x stored as x/64
#define XSCI 64.f
#define FSC  (1.f/256.f)  // ft stored as ft/256
#define WSC  256.f        // W stored as 256*W (256 * 1/256 = 1 in product)

typedef _Float16 f16;
typedef f16 half8 __attribute__((ext_vector_type(8)));
typedef float f32x4 __attribute__((ext_vector_type(4)));
#define MFMA16(a, b, c) __builtin_amdgcn_mfma_f32_16x16x32_f16(a, b, c, 0, 0, 0)

__device__ __forceinline__ float lrelu(float v) { return v > 0.f ? v : 0.01f * v; }
__device__ __forceinline__ int enc(float f) { int i = __float_as_int(f); return i >= 0 ? i : (i ^ 0x7fffffff); }
__device__ __forceinline__ float dec(int k) { int i = k >= 0 ? k : (k ^ 0x7fffffff); return __int_as_float(i); }
__device__ __forceinline__ void split8(const float* v, half8& h, half8& l) {
    #pragma unroll
    for (int e = 0; e < 8; ++e) {
        f16 hh = (f16)v[e]; h[e] = hh; l[e] = (f16)((v[e] - (float)hh) * 2048.f);
    }
}

// src*scale -> f16 hi/lo, 8 elems/thread
__global__ __launch_bounds__(256) void split_scale(
    const float* __restrict__ src, f16* __restrict__ dh, f16* __restrict__ dl, float scale)
{
    long i = ((long)blockIdx.x * 256 + threadIdx.x) * 8;
    float4 a = *(const float4*)&src[i];
    float4 b = *(const float4*)&src[i + 4];
    float v[8] = {a.x * scale, a.y * scale, a.z * scale, a.w * scale,
                  b.x * scale, b.y * scale, b.z * scale, b.w * scale};
    half8 h, l; split8(v, h, l);
    *(half8*)&dh[i] = h; *(half8*)&dl[i] = l;
}

// Wy = gc_w@attn_w^T -> split [L][d][h]; by; w1/w2 splits; FMX init
__global__ __launch_bounds__(256) void prep_wy(
    const float* __restrict__ gc_w, const float* __restrict__ gc_b,
    const float* __restrict__ attn_w,
    f16* __restrict__ WysH, f16* __restrict__ WysL, float* __restrict__ by,
    const float* __restrict__ w1, const float* __restrict__ w2,
    f16* __restrict__ w1h, f16* __restrict__ w1l,
    f16* __restrict__ w2h, f16* __restrict__ w2l, int* __restrict__ FMXi)
{
    int L = blockIdx.x >> 6, d = blockIdx.x & 63;
    int h = threadIdx.x;
    const float* gw = gc_w + (long)L * HH * HH;
    const float* aw = attn_w + (long)L * DD * HH + (long)d * HH;
    float acc = 0.f;
    for (int hp = 0; hp < HH; ++hp) acc += gw[(long)h * HH + hp] * aw[hp];
    f16 hh = (f16)acc;
    WysH[((long)L * DD + d) * HH + h] = hh;
    WysL[((long)L * DD + d) * HH + h] = (f16)((acc - (float)hh) * 2048.f);
    if (h == 0) {
        float ba = 0.f;
        const float* gb = gc_b + (long)L * HH;
        for (int hp = 0; hp < HH; ++hp) ba += gb[hp] * aw[hp];
        by[L * DD + d] = ba;
    }
    int gt = blockIdx.x * 256 + h;   // 32768 threads x 4 = 131072 = 2*65536
    #pragma unroll
    for (int p = 0; p < 4; ++p) {
        int e = gt * 4 + p;
        if (e < 65536) {
            float v = w1[e]; f16 x = (f16)v;
            w1h[e] = x; w1l[e] = (f16)((v - (float)x) * 2048.f);
        } else {
            int e2 = e - 65536;
            float v = w2[e2]; f16 x = (f16)v;
            w2h[e2] = x; w2l[e2] = (f16)((v - (float)x) * 2048.f);
        }
    }
    if (blockIdx.x == 0 && h < 2 * BB) FMXi[h] = enc(-1e30f);
}

// yT[b][d][s] (split of y/64) = (x/64) @ Wy   (MFMA)
__global__ __launch_bounds__(256) void y_mfma(
    const f16* __restrict__ xh, const f16* __restrict__ xl,
    const f16* __restrict__ WyhL, const f16* __restrict__ WylL,
    f16* __restrict__ yTh, f16* __restrict__ yTl)
{
    __shared__ float Ls[64][68];
    const int blk = blockIdx.x;          // b*32 + st
    const int b = blk >> 5, st = blk & 31;
    const long row0 = (long)b * SS + st * 64;
    const int tid = threadIdx.x;
    const int w = tid >> 6, l = tid & 63, lr = l & 15, kg = (l >> 4) * 8;
    const f16* Aph = xh + (row0 + w * 16 + lr) * HH;
    const f16* Apl = xl + (row0 + w * 16 + lr) * HH;
    f32x4 acch[4] = {}, accm[4] = {};
    for (int k0 = 0; k0 < HH; k0 += 32) {
        half8 ah = *(const half8*)(Aph + k0 + kg);
        half8 al = *(const half8*)(Apl + k0 + kg);
        #pragma unroll
        for (int dt = 0; dt < 4; ++dt) {
            long boff = (long)(dt * 16 + lr) * HH + k0 + kg;
            half8 bh = *(const half8*)(WyhL + boff);
            half8 bl = *(const half8*)(WylL + boff);
            acch[dt] = MFMA16(ah, bh, acch[dt]);
            accm[dt] = MFMA16(ah, bl, accm[dt]);
            accm[dt] = MFMA16(al, bh, accm[dt]);
        }
    }
    const int rg0 = (l >> 4) * 4;
    #pragma unroll
    for (int dt = 0; dt < 4; ++dt)
        #pragma unroll
        for (int rr = 0; rr < 4; ++rr)
            Ls[w * 16 + rg0 + rr][dt * 16 + lr] = acch[dt][rr] + accm[dt][rr] * (1.f / 2048.f);
    __syncthreads();
    int d = tid >> 2, sq = (tid & 3) * 16;
    long obase = ((long)b * DD + d) * SS + st * 64 + sq;
    float v0[8], v1[8];
    #pragma unroll
    for (int e = 0; e < 8; ++e) { v0[e] = Ls[sq + e][d]; v1[e] = Ls[sq + 8 + e][d]; }
    half8 h0, l0, h1, l1; split8(v0, h0, l0); split8(v1, h1, l1);
    *(half8*)(yTh + obase) = h0; *(half8*)(yTh + obase + 8) = h1;
    *(half8*)(yTl + obase) = l0; *(half8*)(yTl + obase + 8) = l1;
}

// FTP[ky][b][i][d] = adj[i,kslice] @ y[kslice,d]   (MFMA, on-the-fly adj split)
__global__ __launch_bounds__(256) void ftp_mfma(
    const float* __restrict__ adjB,
    const f16* __restrict__ yTh, const f16* __restrict__ yTl,
    float* __restrict__ FTP)
{
    const int b = blockIdx.z;
    const int i0 = blockIdx.x * 64;
    const int ky = blockIdx.y;
    const int tid = threadIdx.x;
    const int w = tid >> 6, l = tid & 63;
    const int lr = l & 15, kg = (l >> 4) * 8;
    const float* Arow = adjB + (long)b * 2 * SS * SS + (long)(i0 + w * 16 + lr) * SS;
    const f16* Bh = yTh + ((long)b * DD + lr) * SS;
    const f16* Bl = yTl + ((long)b * DD + lr) * SS;

    f32x4 acch[4] = {}, accm[4] = {};
    for (int ks = 0; ks < KSL; ks += 32) {
        int k = ky * KSL + ks + kg;
        float4 a0 = *(const float4*)(Arow + k);
        float4 a1 = *(const float4*)(Arow + k + 4);
        float av[8] = {a0.x, a0.y, a0.z, a0.w, a1.x, a1.y, a1.z, a1.w};
        half8 ah, al; split8(av, ah, al);
        #pragma unroll
        for (int dt = 0; dt < 4; ++dt) {
            long off = (long)dt * 16 * SS + k;
            half8 bh = *(const half8*)(Bh + off);
            half8 bl = *(const half8*)(Bl + off);
            acch[dt] = MFMA16(ah, bh, acch[dt]);
            accm[dt] = MFMA16(ah, bl, accm[dt]);
            accm[dt] = MFMA16(al, bh, accm[dt]);
        }
    }
    const int rg0 = (l >> 4) * 4;
    #pragma unroll
    for (int dt = 0; dt < 4; ++dt)
        #pragma unroll
        for (int rr = 0; rr < 4; ++rr) {
            long iD = i0 + w * 16 + rg0 + rr;
            FTP[(((long)ky * BB + b) * SS + iD) * DD + dt * 16 + lr] =
                (acch[dt][rr] + accm[dt][rr] * (1.f / 2048.f)) * XSCI;
        }
}

// ft = sum_ky FTP + by; F = ft@attn_a; fT split (ft/256); atomic fmax
__global__ __launch_bounds__(256) void reduce_ft_t(
    const float* __restrict__ FTP, const float* __restrict__ byL,
    const float* __restrict__ aaL, float* __restrict__ F,
    f16* __restrict__ fTh, f16* __restrict__ fTl, int* __restrict__ fmxSlot)
{
    __shared__ float Ls[64][68];
    const int blk = blockIdx.x;
    const int b = blk >> 5, st = blk & 31;
    const int s0 = st * 64;
    const int tid = threadIdx.x;
    {
        int c4 = (tid & 15) * 4, r0 = tid >> 4;
        float4 bb4 = *(const float4*)&byL[c4];
        #pragma unroll
        for (int p = 0; p < 4; ++p) {
            int r = r0 + 16 * p;
            long rowoff = ((long)b * SS + s0 + r) * DD + c4;
            float4 v = *(const float4*)&FTP[rowoff];
            #pragma unroll
            for (int ky = 1; ky < NKY; ++ky) {
                float4 u = *(const float4*)&FTP[(long)ky * BB * SS * DD + rowoff];
                v.x += u.x; v.y += u.y; v.z += u.z; v.w += u.w;
            }
            v.x += bb4.x; v.y += bb4.y; v.z += bb4.z; v.w += bb4.w;
            *(float4*)&Ls[r][c4] = v;
        }
    }
    __syncthreads();
    {   // F[row] = ft @ attn_a  + per-batch fmax atomic
        int r = tid >> 2, q = tid & 3;
        float dot = 0.f;
        #pragma unroll
        for (int e = 0; e < 16; ++e) dot += Ls[r][q * 16 + e] * aaL[q * 16 + e];
        dot += __shfl_xor(dot, 1, 64);
        dot += __shfl_xor(dot, 2, 64);
        if (q == 0) F[b * SS + s0 + r] = dot;
        float m = dot;
        m = fmaxf(m, __shfl_down(m, 32, 64));
        m = fmaxf(m, __shfl_down(m, 16, 64));
        m = fmaxf(m, __shfl_down(m, 8, 64));
        m = fmaxf(m, __shfl_down(m, 4, 64));
        if ((tid & 63) == 0) atomicMax(fmxSlot + b, enc(m));
    }
    int d = tid >> 2, sq = (tid & 3) * 16;
    long obase = ((long)b * DD + d) * SS + s0 + sq;
    float v0[8], v1[8];
    #pragma unroll
    for (int e = 0; e < 8; ++e) { v0[e] = Ls[sq + e][d] * FSC; v1[e] = Ls[sq + 8 + e][d] * FSC; }
    half8 h0, l0, h1, l1; split8(v0, h0, l0); split8(v1, h1, l1);
    *(half8*)(fTh + obase) = h0; *(half8*)(fTh + obase + 8) = h1;
    *(half8*)(fTl + obase) = l0; *(half8*)(fTl + obase + 8) = l1;
}

// Column softmax sums, bound M_j = lrelu(fmax_b + f_j) + 8. Branch-free.
__global__ __launch_bounds__(256) void col_stats_part(
    const float* __restrict__ biasb, const float* __restrict__ f,
    const int* __restrict__ fmxSlot,
    float* __restrict__ partS, float* __restrict__ Mv)
{
    __shared__ float fs[SS / NCH];
    const int b = blockIdx.z;
    const int chunk = blockIdx.y;
    const int j0 = blockIdx.x * 1024 + threadIdx.x * 4;
    const float* bb = biasb + (long)b * 2 * SS * SS;
    const int ILEN = SS / NCH;
    const int ibase = chunk * ILEN;

    if (threadIdx.x < ILEN) fs[threadIdx.x] = f[b * SS + ibase + threadIdx.x];

    float fj[4], M[4], s[4] = {0.f, 0.f, 0.f, 0.f};
    const float fmx = dec(fmxSlot[b]);
    #pragma unroll
    for (int q = 0; q < 4; ++q) {
        fj[q] = f[b * SS + j0 + q];
        M[q] = lrelu(fmx + fj[q]) + 8.f;
    }
    __syncthreads();

    for (int ii = 0; ii < ILEN; ii += 2) {
        float fi0 = fs[ii], fi1 = fs[ii + 1];
        float4 b0 = *(const float4*)&bb[(long)(ibase + ii) * SS + j0];
        float4 b1 = *(const float4*)&bb[(long)(ibase + ii + 1) * SS + j0];
        s[0] += __expf(lrelu(fi0 + fj[0]) + b0.x - M[0]);
        s[1] += __expf(lrelu(fi0 + fj[1]) + b0.y - M[1]);
        s[2] += __expf(lrelu(fi0 + fj[2]) + b0.z - M[2]);
        s[3] += __expf(lrelu(fi0 + fj[3]) + b0.w - M[3]);
        s[0] += __expf(lrelu(fi1 + fj[0]) + b1.x - M[0]);
        s[1] += __expf(lrelu(fi1 + fj[1]) + b1.y - M[1]);
        s[2] += __expf(lrelu(fi1 + fj[2]) + b1.z - M[2]);
        s[3] += __expf(lrelu(fi1 + fj[3]) + b1.w - M[3]);
    }
    #pragma unroll
    for (int q = 0; q < 4; ++q)
        partS[((long)chunk * BB + b) * SS + j0 + q] = s[q];
    if (chunk == 0) {
        #pragma unroll
        for (int q = 0; q < 4; ++q) Mv[b * SS + j0 + q] = M[q];
    }
}

__global__ __launch_bounds__(256) void col_stats_merge(
    const float* __restrict__ partS, float* __restrict__ Sinv)
{
    int idx = blockIdx.x * 256 + threadIdx.x;
    int b = idx / SS, j = idx % SS;
    float s = 0.f;
    #pragma unroll
    for (int c = 0; c < NCH; ++c)
        s += partS[((long)c * BB + b) * SS + j];
    Sinv[idx] = 1.f / s;
}

// PVP[jy][b][i][d]: W built per-lane straight into A-fragment (no LDS, no syncs)
__global__ __launch_bounds__(256) void pvp_mfma(
    const float* __restrict__ biasb, const float* __restrict__ f,
    const float* __restrict__ Mv, const float* __restrict__ Sinv,
    const f16* __restrict__ fTh, const f16* __restrict__ fTl,
    float* __restrict__ PVP)
{
    const int b = blockIdx.z;
    const int i0 = blockIdx.x * 64;
    const int jy = blockIdx.y;
    const int tid = threadIdx.x;
    const int w = tid >> 6, l = tid & 63, lr = l & 15, kg = (l >> 4) * 8;
    const int irow = i0 + w * 16 + lr;
    const float fi = f[b * SS + irow];
    const float* brow = biasb + (long)b * 2 * SS * SS + (long)irow * SS;
    const float* fb = f + b * SS;
    const float* mb = Mv + b * SS;
    const float* sb = Sinv + b * SS;
    const f16* Bh = fTh + ((long)b * DD + lr) * SS;
    const f16* Bl = fTl + ((long)b * DD + lr) * SS;

    f32x4 acch[4] = {}, accm[4] = {};
    for (int jc = 0; jc < JSL; jc += 32) {
        const int jb = jy * JSL + jc + kg;
        float4 bs0 = *(const float4*)(brow + jb);
        float4 bs1 = *(const float4*)(brow + jb + 4);
        float4 fj0 = *(const float4*)(fb + jb);
        float4 fj1 = *(const float4*)(fb + jb + 4);
        float4 mj0 = *(const float4*)(mb + jb);
        float4 mj1 = *(const float4*)(mb + jb + 4);
        float4 sj0 = *(const float4*)(sb + jb);
        float4 sj1 = *(const float4*)(sb + jb + 4);
        float wv[8];
        wv[0] = __expf(lrelu(fi + fj0.x) + bs0.x - mj0.x) * sj0.x * WSC;
        wv[1] = __expf(lrelu(fi + fj0.y) + bs0.y - mj0.y) * sj0.y * WSC;
        wv[2] = __expf(lrelu(fi + fj0.z) + bs0.z - mj0.z) * sj0.z * WSC;
        wv[3] = __expf(lrelu(fi + fj0.w) + bs0.w - mj0.w) * sj0.w * WSC;
        wv[4] = __expf(lrelu(fi + fj1.x) + bs1.x - mj1.x) * sj1.x * WSC;
        wv[5] = __expf(lrelu(fi + fj1.y) + bs1.y - mj1.y) * sj1.y * WSC;
        wv[6] = __expf(lrelu(fi + fj1.z) + bs1.z - mj1.z) * sj1.z * WSC;
        wv[7] = __expf(lrelu(fi + fj1.w) + bs1.w - mj1.w) * sj1.w * WSC;
        half8 ah, al; split8(wv, ah, al);
        #pragma unroll
        for (int dt = 0; dt < 4; ++dt) {
            long off = (long)dt * 16 * SS + jb;
            half8 bh = *(const half8*)(Bh + off);
            half8 bl = *(const half8*)(Bl + off);
            acch[dt] = MFMA16(ah, bh, acch[dt]);
            accm[dt] = MFMA16(ah, bl, accm[dt]);
            accm[dt] = MFMA16(al, bh, accm[dt]);
        }
    }
    const int rg0 = (l >> 4) * 4;
    #pragma unroll
    for (int dt = 0; dt < 4; ++dt)
        #pragma unroll
        for (int rr = 0; rr < 4; ++rr) {
            long iD = i0 + w * 16 + rg0 + rr;
            PVP[(((long)jy * BB + b) * SS + iD) * DD + dt * 16 + lr] =
                acch[dt][rr] + accm[dt][rr] * (1.f / 2048.f);   // WSC*FSC = 1
        }
}

// x_out = tile(lrelu(sum_jy PVP), HEADS) + x_in; optional x/64 split for next layer
__global__ __launch_bounds__(256) void pv_combine8(
    const float* __restrict__ PVP, const float* __restrict__ xin,
    float* __restrict__ xout, f16* __restrict__ xh, f16* __restrict__ xl,
    int writeSplit)
{
    int row = blockIdx.x * 4 + (threadIdx.x >> 6);
    int d = threadIdx.x & 63;
    float v = 0.f;
    #pragma unroll
    for (int jy = 0; jy < NJY; ++jy)
        v += PVP[((long)jy * BB * SS + row) * DD + d];
    v = lrelu(v);
    #pragma unroll
    for (int rep = 0; rep < 4; ++rep) {
        long off = (long)row * HH + rep * DD + d;
        float o = v + xin[off];
        xout[off] = o;
        if (writeSplit) {
            float sv = o * XSC;
            f16 hh = (f16)sv;
            xh[off] = hh;
            xl[off] = (f16)((sv - (float)hh) * 2048.f);
        }
    }
}

// g = ln_a*(x-mean)/(std+eps) + ln_b + x0 ; writes g f32 and g hi/lo
__global__ __launch_bounds__(256) void layernorm_g(
    const float* __restrict__ x, const float* __restrict__ x0,
    const float* __restrict__ lna, const float* __restrict__ lnb,
    float* __restrict__ g, f16* __restrict__ gh, f16* __restrict__ gl)
{
    __shared__ float red[8];
    long row = blockIdx.x;
    int t = threadIdx.x;
    int wave = t >> 6, lane = t & 63;
    float v = x[row * HH + t];

    float sum = v;
    #pragma unroll
    for (int off = 32; off; off >>= 1) sum += __shfl_down(sum, off, 64);
    if (lane == 0) red[wave] = sum;
    __syncthreads();
    if (t < 64) {
        float s = (lane < 4) ? red[lane] : 0.f;
        s += __shfl_down(s, 2, 64);
        s += __shfl_down(s, 1, 64);
        if (lane == 0) red[4] = s / HH;
    }
    __syncthreads();
    float mean = red[4];
    float d = v - mean;
    float sq = d * d;
    #pragma unroll
    for (int off = 32; off; off >>= 1) sq += __shfl_down(sq, off, 64);
    __syncthreads();
    if (lane == 0) red[wave] = sq;
    __syncthreads();
    if (t < 64) {
        float s = (lane < 4) ? red[lane] : 0.f;
        s += __shfl_down(s, 2, 64);
        s += __shfl_down(s, 1, 64);
        if (lane == 0) red[5] = sqrtf(s / (HH - 1));
    }
    __syncthreads();
    float stdv = red[5];
    float gv = lna[t] * d / (stdv + 1e-6f) + lnb[t] + x0[row * HH + t];
    g[row * HH + t] = gv;
    f16 hh = (f16)gv;
    gh[row * HH + t] = hh;
    gl[row * HH + t] = (f16)((gv - (float)hh) * 2048.f);
}

// C = A@B^T (+bias)(relu)(+res). A split [M][256]; B split [256][256] (row=n).
// outF f32 OR outH/outL split.
__global__ __launch_bounds__(256) void ffn_mfma(
    const f16* __restrict__ Ah, const f16* __restrict__ Al,
    const f16* __restrict__ Bh, const f16* __restrict__ Bl,
    const float* __restrict__ bias, const float* __restrict__ res,
    float* __restrict__ outF, f16* __restrict__ outH, f16* __restrict__ outL,
    int doRelu)
{
    __shared__ float Ls[64][68];
    const int i0 = blockIdx.x * 64, j0 = blockIdx.y * 64;
    const int tid = threadIdx.x;
    const int w = tid >> 6, l = tid & 63, lr = l & 15, kg = (l >> 4) * 8;
    const f16* Aph = Ah + ((long)i0 + w * 16 + lr) * HH;
    const f16* Apl = Al + ((long)i0 + w * 16 + lr) * HH;
    f32x4 acch[4] = {}, accm[4] = {};
    for (int k0 = 0; k0 < HH; k0 += 32) {
        half8 ah = *(const half8*)(Aph + k0 + kg);
        half8 al = *(const half8*)(Apl + k0 + kg);
        #pragma unroll
        for (int dt = 0; dt < 4; ++dt) {
            long boff = ((long)(j0 + dt * 16 + lr)) * HH + k0 + kg;
            half8 bh = *(const half8*)(Bh + boff);
            half8 bl = *(const half8*)(Bl + boff);
            acch[dt] = MFMA16(ah, bh, acch[dt]);
            accm[dt] = MFMA16(ah, bl, accm[dt]);
            accm[dt] = MFMA16(al, bh, accm[dt]);
        }
    }
    const int rg0 = (l >> 4) * 4;
    #pragma unroll
    for (int dt = 0; dt < 4; ++dt) {
        float bj = bias[j0 + dt * 16 + lr];
        #pragma unroll
        for (int rr = 0; rr < 4; ++rr) {
            float v = acch[dt][rr] + accm[dt][rr] * (1.f / 2048.f) + bj;
            if (doRelu) v = fmaxf(v, 0.f);
            Ls[w * 16 + rg0 + rr][dt * 16 + lr] = v;
        }
    }
    __syncthreads();
    int s = tid >> 2, nq = (tid & 3) * 16;
    long go = ((long)i0 + s) * HH + j0 + nq;
    if (outF) {
        #pragma unroll
        for (int q = 0; q < 4; ++q) {
            float4 v = *(float4*)&Ls[s][nq + q * 4];
            if (res) {
                float4 r = *(const float4*)&res[go + q * 4];
                v.x += r.x; v.y += r.y; v.z += r.z; v.w += r.w;
            }
            *(float4*)&outF[go + q * 4] = v;
        }
    } else {
        float v0[8], v1[8];
        #pragma unroll
        for (int e = 0; e < 8; ++e) { v0[e] = Ls[s][nq + e]; v1[e] = Ls[s][nq + 8 + e]; }
        half8 h0, l0, h1, l1; split8(v0, h0, l0); split8(v1, h1, l1);
        *(half8*)&outH[go] = h0; *(half8*)&outH[go + 8] = h1;
        *(half8*)&outL[go] = l0; *(half8*)&outL[go + 8] = l1;
    }
}

extern "C" void kernel_launch(void* const* d_in, const int* in_sizes, int n_in,
                              void* d_out, int out_size, void* d_ws, size_t ws_size,
                              hipStream_t stream)
{
    const float* inputs = (const float*)d_in[0];
    const float* graphs = (const float*)d_in[1];
    const float* biases = (const float*)d_in[2];
    const float* gc_w   = (const float*)d_in[3];
    const float* gc_b   = (const float*)d_in[4];
    const float* attn_w = (const float*)d_in[5];
    const float* attn_a = (const float*)d_in[6];
    const float* ln_a   = (const float*)d_in[7];
    const float* ln_b   = (const float*)d_in[8];
    const float* w1     = (const float*)d_in[9];
    const float* w1b    = (const float*)d_in[10];
    const float* w2     = (const float*)d_in[11];
    const float* w2b    = (const float*)d_in[12];
    float* out = (float*)d_out;

    // ---- workspace layout (float offsets), ~47 MB total ----
    float* ws   = (float*)d_ws;
    float* X    = ws;                     // 2,097,152
    float* G    = ws + 2097152;           // 2,097,152
    float* FTPV = ws + 4194304;           // 4,194,304 (FTP/PVP 8 slices; gh/gl/h1h/h1l after layers)
    float* PTS  = ws + 8388608;           // 524,288
    float* F    = ws + 8912896;           // 8,192
    float* Mv   = ws + 8921088;           // 8,192
    float* Sv   = ws + 8929280;           // 8,192
    float* by   = ws + 8937472;           // 128
    int*   FMXi = (int*)(ws + 8937600);   // 32
    f16* WysH   = (f16*)(ws + 8937728);   // 32,768 halves
    f16* WysL   = (f16*)(ws + 8954112);
    f16* yTh    = (f16*)(ws + 8970496);   // 524,288 halves each
    f16* yTl    = (f16*)(ws + 9232640);
    f16* fTh    = (f16*)(ws + 9494784);
    f16* fTl    = (f16*)(ws + 9756928);
    f16* xh     = (f16*)(ws + 10019072);  // 2,097,152 halves each
    f16* xl     = (f16*)(ws + 11067648);
    f16* w1h    = (f16*)(ws + 12116224);  // 65,536 halves each
    f16* w1l    = (f16*)(ws + 12148992);
    f16* w2h    = (f16*)(ws + 12181760);
    f16* w2l    = (f16*)(ws + 12214528);  // end 12,247,296 floats (~46.7 MB)

    float* FTP = FTPV;
    float* PVP = FTPV;
    f16* gh  = (f16*)(FTPV);              // FTP/PVP dead after layers
    f16* gl  = (f16*)(FTPV + 1048576);
    f16* h1h = (f16*)(FTPV + 2097152);
    f16* h1l = (f16*)(FTPV + 3145728);

    const float* adjBase  = graphs + (long)SS * SS;  // [:, TYPE_IDX=1]
    const float* biasBase = biases + (long)SS * SS;

    prep_wy<<<128, 256, 0, stream>>>(gc_w, gc_b, attn_w, WysH, WysL, by,
                                     w1, w2, w1h, w1l, w2h, w2l, FMXi);
    split_scale<<<1024, 256, 0, stream>>>(inputs, xh, xl, XSC);

    for (int L = 0; L < NLAYERS; ++L) {
        y_mfma<<<128, 256, 0, stream>>>(xh, xl,
            WysH + (long)L * DD * HH, WysL + (long)L * DD * HH, yTh, yTl);
        ftp_mfma<<<dim3(32, NKY, BB), 256, 0, stream>>>(adjBase, yTh, yTl, FTP);
        reduce_ft_t<<<128, 256, 0, stream>>>(FTP, by + L * DD, attn_a + (long)L * DD,
                                             F, fTh, fTl, FMXi + L * BB);
        col_stats_part<<<dim3(2, NCH, BB), 256, 0, stream>>>(biasBase, F, FMXi + L * BB, PTS, Mv);
        col_stats_merge<<<32, 256, 0, stream>>>(PTS, Sv);
        pvp_mfma<<<dim3(32, NJY, BB), 256, 0, stream>>>(biasBase, F, Mv, Sv, fTh, fTl, PVP);
        pv_combine8<<<2048, 256, 0, stream>>>(PVP, (L == 0) ? inputs : X, X,
                                              xh, xl, (L == 0) ? 1 : 0);
    }

    layernorm_g<<<BB * SS, 256, 0, stream>>>(X, inputs, ln_a, ln_b, G, gh, gl);
    ffn_mfma<<<dim3(128, 4), 256, 0, stream>>>(gh, gl, w1h, w1l, w1b,
                                               nullptr, nullptr, h1h, h1l, 1);
    ffn_mfma<<<dim3(128, 4), 256, 0, stream>>>(h1h, h1l, w2h, w2l, w2b,
                                               G, out, nullptr, nullptr, 0);
}